// Round 1
// baseline (2199.089 us; speedup 1.0000x reference)
//
#include <hip/hip_runtime.h>
#include <hip/hip_bf16.h>
#include <cstdint>
#include <cstddef>

#define SLEN 2048
#define NHEAD 16
#define HDIM 64

// ---------------------------------------------------------------------------
// GEMM1: qkv = x @ Wattn + bias  (M=rows, N=3072, K=1024)
// Scatters output into Q/K/V buffers laid out (bh, s, d) contiguous.
// 128x128 tile, 256 threads, 8x8 microtile, BK=16, fp32 vector FMA.
// ---------------------------------------------------------------------------
__global__ __launch_bounds__(256, 2) void qkv_gemm(
    const float* __restrict__ X, const float* __restrict__ W,
    const float* __restrict__ Bias,
    float* __restrict__ Qd, float* __restrict__ Kd, float* __restrict__ Vd,
    int m0)
{
  __shared__ float As[16][132];   // [k][m] transposed
  __shared__ float Bs[16][132];   // [k][n]
  const int tid = threadIdx.x;
  const int tr = tid >> 4;        // 0..15
  const int tc = tid & 15;        // 0..15
  const int mtile = blockIdx.y * 128;   // local row base
  const int nbase = blockIdx.x * 128;

  float acc[8][8];
  #pragma unroll
  for (int i = 0; i < 8; i++)
    #pragma unroll
    for (int j = 0; j < 8; j++) acc[i][j] = 0.f;

  float bias_[8];
  #pragma unroll
  for (int j = 0; j < 8; j++) bias_[j] = Bias[nbase + tc*8 + j];

  const int r_a = tid >> 2;            // 0..63
  const int c_a = (tid & 3) * 4;       // 0,4,8,12
  const int kk_b = tid >> 5;           // 0..7
  const int c_b = (tid & 31) * 4;      // 0..124

  for (int k0 = 0; k0 < 1024; k0 += 16) {
    #pragma unroll
    for (int ld = 0; ld < 2; ld++) {
      int r = r_a + ld*64;
      float4 a4 = *(const float4*)(X + (size_t)(m0 + mtile + r)*1024 + k0 + c_a);
      As[c_a+0][r] = a4.x; As[c_a+1][r] = a4.y;
      As[c_a+2][r] = a4.z; As[c_a+3][r] = a4.w;
    }
    #pragma unroll
    for (int ld = 0; ld < 2; ld++) {
      int kk = kk_b + ld*8;
      float4 b4 = *(const float4*)(W + (size_t)(k0 + kk)*3072 + nbase + c_b);
      *(float4*)&Bs[kk][c_b] = b4;
    }
    __syncthreads();
    #pragma unroll
    for (int kk = 0; kk < 16; kk++) {
      float4 a0 = *(const float4*)&As[kk][tr*8];
      float4 a1 = *(const float4*)&As[kk][tr*8+4];
      float4 b0 = *(const float4*)&Bs[kk][tc*8];
      float4 b1 = *(const float4*)&Bs[kk][tc*8+4];
      float av[8] = {a0.x,a0.y,a0.z,a0.w,a1.x,a1.y,a1.z,a1.w};
      float bv[8] = {b0.x,b0.y,b0.z,b0.w,b1.x,b1.y,b1.z,b1.w};
      #pragma unroll
      for (int i = 0; i < 8; i++)
        #pragma unroll
        for (int j = 0; j < 8; j++)
          acc[i][j] += av[i]*bv[j];
    }
    __syncthreads();
  }
  // epilogue: scatter to q/k/v in (bh, s, d) layout
  #pragma unroll
  for (int i = 0; i < 8; i++) {
    int lr = mtile + tr*8 + i;
    int bl = lr >> 11, s = lr & 2047;
    #pragma unroll
    for (int j4 = 0; j4 < 8; j4 += 4) {
      int n = nbase + tc*8 + j4;
      int which = n >> 10, rem = n & 1023;
      int h = rem >> 6, d = rem & 63;
      float* base = which == 0 ? Qd : (which == 1 ? Kd : Vd);
      float4 o;
      o.x = acc[i][j4+0] + bias_[j4+0];
      o.y = acc[i][j4+1] + bias_[j4+1];
      o.z = acc[i][j4+2] + bias_[j4+2];
      o.w = acc[i][j4+3] + bias_[j4+3];
      *(float4*)(base + (((size_t)(bl*16 + h))*2048 + s)*64 + d) = o;
    }
  }
}

// ---------------------------------------------------------------------------
// Flash attention: one block per (bh, 64 q-rows). K/V tiles of 32 keys in LDS.
// Thread t: q-row r = t>>2, lane-group c = t&3. Scores: keys 4j+c (j=0..7).
// PV: dims d0 = c*16 .. +15. Online softmax; shfl_xor(1,2) reduces over c.
// Output overwrites Q buffer (each block reads its own Q tile first).
// ---------------------------------------------------------------------------
__global__ __launch_bounds__(256, 2) void attn64(
    const float* __restrict__ Q, const float* __restrict__ K,
    const float* __restrict__ V, const float* __restrict__ mask,
    float* __restrict__ O, int b0)
{
  __shared__ float Qs[64][68];
  __shared__ float Ks[32][68];
  __shared__ float Vs[32][68];
  __shared__ float Pt[32][68];   // [key][row]
  const int tid = threadIdx.x;
  const int qt  = blockIdx.x & 31;
  const int bh  = blockIdx.x >> 5;
  const int bglob = b0 + (bh >> 4);
  const float* qbase = Q + ((size_t)bh*SLEN + qt*64)*HDIM;
  const float* kbase = K + (size_t)bh*SLEN*HDIM;
  const float* vbase = V + (size_t)bh*SLEN*HDIM;
  const float* mrow  = mask + (size_t)bglob*SLEN;

  const int r  = tid >> 2;
  const int c  = tid & 3;
  const int d0 = c * 16;

  #pragma unroll
  for (int i = 0; i < 4; i++) {
    int ch = tid + i*256;
    int rr = ch >> 4, c4 = (ch & 15)*4;
    *(float4*)&Qs[rr][c4] = *(const float4*)(qbase + (size_t)rr*HDIM + c4);
  }

  float m = -INFINITY, l = 0.f;
  float acc[16];
  #pragma unroll
  for (int i = 0; i < 16; i++) acc[i] = 0.f;

  for (int kt = 0; kt < SLEN/32; kt++) {
    __syncthreads();   // previous PV / first-iter no-op
    #pragma unroll
    for (int i = 0; i < 2; i++) {
      int ch = tid + i*256;
      int rr = ch >> 4, c4 = (ch & 15)*4;
      *(float4*)&Ks[rr][c4] = *(const float4*)(kbase + (size_t)(kt*32 + rr)*HDIM + c4);
      *(float4*)&Vs[rr][c4] = *(const float4*)(vbase + (size_t)(kt*32 + rr)*HDIM + c4);
    }
    __syncthreads();
    // scores
    float sc[8];
    #pragma unroll
    for (int j = 0; j < 8; j++) sc[j] = 0.f;
    #pragma unroll
    for (int dd = 0; dd < 64; dd += 4) {
      float4 q4 = *(const float4*)&Qs[r][dd];
      #pragma unroll
      for (int j = 0; j < 8; j++) {
        float4 k4 = *(const float4*)&Ks[j*4 + c][dd];
        sc[j] += q4.x*k4.x + q4.y*k4.y + q4.z*k4.z + q4.w*k4.w;
      }
    }
    float tmax = -INFINITY;
    #pragma unroll
    for (int j = 0; j < 8; j++) {
      sc[j] = sc[j]*0.125f + mrow[kt*32 + j*4 + c];
      tmax = fmaxf(tmax, sc[j]);
    }
    tmax = fmaxf(tmax, __shfl_xor(tmax, 1));
    tmax = fmaxf(tmax, __shfl_xor(tmax, 2));
    float mnew = fmaxf(m, tmax);
    float corr = __expf(m - mnew);
    float psum = 0.f;
    #pragma unroll
    for (int j = 0; j < 8; j++) {
      float p = __expf(sc[j] - mnew);
      psum += p;
      Pt[j*4 + c][r] = p;
    }
    psum += __shfl_xor(psum, 1);
    psum += __shfl_xor(psum, 2);
    l = l*corr + psum;
    m = mnew;
    #pragma unroll
    for (int i = 0; i < 16; i++) acc[i] *= corr;
    __syncthreads();   // Pt visible
    #pragma unroll 4
    for (int key = 0; key < 32; key++) {
      float p = Pt[key][r];
      const float* vrow = &Vs[key][d0];
      float4 v0 = *(const float4*)(vrow);
      float4 v1 = *(const float4*)(vrow+4);
      float4 v2 = *(const float4*)(vrow+8);
      float4 v3 = *(const float4*)(vrow+12);
      acc[0]  += p*v0.x; acc[1]  += p*v0.y; acc[2]  += p*v0.z; acc[3]  += p*v0.w;
      acc[4]  += p*v1.x; acc[5]  += p*v1.y; acc[6]  += p*v1.z; acc[7]  += p*v1.w;
      acc[8]  += p*v2.x; acc[9]  += p*v2.y; acc[10] += p*v2.z; acc[11] += p*v2.w;
      acc[12] += p*v3.x; acc[13] += p*v3.y; acc[14] += p*v3.z; acc[15] += p*v3.w;
    }
  }
  float inv = 1.f / l;
  float* ob = O + ((size_t)bh*SLEN + qt*64 + r)*HDIM + d0;
  float4 o0 = {acc[0]*inv,  acc[1]*inv,  acc[2]*inv,  acc[3]*inv};
  float4 o1 = {acc[4]*inv,  acc[5]*inv,  acc[6]*inv,  acc[7]*inv};
  float4 o2 = {acc[8]*inv,  acc[9]*inv,  acc[10]*inv, acc[11]*inv};
  float4 o3 = {acc[12]*inv, acc[13]*inv, acc[14]*inv, acc[15]*inv};
  *(float4*)(ob)    = o0;
  *(float4*)(ob+4)  = o1;
  *(float4*)(ob+8)  = o2;
  *(float4*)(ob+12) = o3;
}

// ---------------------------------------------------------------------------
// GEMM2: out = merge_heads(a) @ Wproj + bias  (M=rows, N=1024, K=1024)
// A gathered from (bh, s, d) layout (head-merge folded into the K index).
// ---------------------------------------------------------------------------
__global__ __launch_bounds__(256, 2) void proj_gemm(
    const float* __restrict__ A, const float* __restrict__ W,
    const float* __restrict__ Bias,
    float* __restrict__ Out, int m0)
{
  __shared__ float As[16][132];
  __shared__ float Bs[16][132];
  const int tid = threadIdx.x;
  const int tr = tid >> 4, tc = tid & 15;
  const int mtile = blockIdx.y * 128;
  const int nbase = blockIdx.x * 128;

  float acc[8][8];
  #pragma unroll
  for (int i = 0; i < 8; i++)
    #pragma unroll
    for (int j = 0; j < 8; j++) acc[i][j] = 0.f;

  float bias_[8];
  #pragma unroll
  for (int j = 0; j < 8; j++) bias_[j] = Bias[nbase + tc*8 + j];

  const int r_a = tid >> 2;
  const int c_a = (tid & 3) * 4;
  const int kk_b = tid >> 5;
  const int c_b = (tid & 31) * 4;

  for (int k0 = 0; k0 < 1024; k0 += 16) {
    int h = k0 >> 6, dblk = k0 & 63;
    #pragma unroll
    for (int ld = 0; ld < 2; ld++) {
      int rr = r_a + ld*64;
      int lr = mtile + rr;
      int bl = lr >> 11, s = lr & 2047;
      float4 a4 = *(const float4*)(A + (((size_t)(bl*16 + h))*2048 + s)*64 + dblk + c_a);
      As[c_a+0][rr] = a4.x; As[c_a+1][rr] = a4.y;
      As[c_a+2][rr] = a4.z; As[c_a+3][rr] = a4.w;
    }
    #pragma unroll
    for (int ld = 0; ld < 2; ld++) {
      int kk = kk_b + ld*8;
      float4 b4 = *(const float4*)(W + (size_t)(k0 + kk)*1024 + nbase + c_b);
      *(float4*)&Bs[kk][c_b] = b4;
    }
    __syncthreads();
    #pragma unroll
    for (int kk = 0; kk < 16; kk++) {
      float4 a0 = *(const float4*)&As[kk][tr*8];
      float4 a1 = *(const float4*)&As[kk][tr*8+4];
      float4 b0 = *(const float4*)&Bs[kk][tc*8];
      float4 b1 = *(const float4*)&Bs[kk][tc*8+4];
      float av[8] = {a0.x,a0.y,a0.z,a0.w,a1.x,a1.y,a1.z,a1.w};
      float bv[8] = {b0.x,b0.y,b0.z,b0.w,b1.x,b1.y,b1.z,b1.w};
      #pragma unroll
      for (int i = 0; i < 8; i++)
        #pragma unroll
        for (int j = 0; j < 8; j++)
          acc[i][j] += av[i]*bv[j];
    }
    __syncthreads();
  }
  #pragma unroll
  for (int i = 0; i < 8; i++) {
    int lr = mtile + tr*8 + i;
    float* orow = Out + (size_t)(m0 + lr)*1024 + nbase + tc*8;
    #pragma unroll
    for (int j4 = 0; j4 < 8; j4 += 4) {
      float4 o;
      o.x = acc[i][j4+0] + bias_[j4+0];
      o.y = acc[i][j4+1] + bias_[j4+1];
      o.z = acc[i][j4+2] + bias_[j4+2];
      o.w = acc[i][j4+3] + bias_[j4+3];
      *(float4*)(orow + j4) = o;
    }
  }
}

extern "C" void kernel_launch(void* const* d_in, const int* in_sizes, int n_in,
                              void* d_out, int out_size, void* d_ws, size_t ws_size,
                              hipStream_t stream) {
  const float* x     = (const float*)d_in[0];
  const float* amask = (const float*)d_in[1];
  const float* wat   = (const float*)d_in[2];
  const float* bat   = (const float*)d_in[3];
  const float* wpr   = (const float*)d_in[4];
  const float* bpr   = (const float*)d_in[5];
  float* out = (float*)d_out;

  const size_t PB = (size_t)NHEAD * SLEN * HDIM;  // floats per batch per tensor
  int bc;
  if (ws_size >= 3 * (size_t)4 * PB * sizeof(float))      bc = 4;
  else if (ws_size >= 3 * (size_t)2 * PB * sizeof(float)) bc = 2;
  else                                                    bc = 1;

  for (int b0 = 0; b0 < 4; b0 += bc) {
    float* Qd = (float*)d_ws;
    float* Kd = Qd + (size_t)bc * PB;
    float* Vd = Kd + (size_t)bc * PB;
    int Mrows = bc * SLEN;
    dim3 g1(24, Mrows / 128);
    qkv_gemm<<<g1, dim3(256), 0, stream>>>(x, wat, bat, Qd, Kd, Vd, b0 * SLEN);
    attn64<<<dim3(bc * NHEAD * (SLEN/64)), dim3(256), 0, stream>>>(
        Qd, Kd, Vd, amask, Qd, b0);
    dim3 g2(8, Mrows / 128);
    proj_gemm<<<g2, dim3(256), 0, stream>>>(Qd, wpr, bpr, out, b0 * SLEN);
  }
}

// Round 2
// 1044.974 us; speedup vs baseline: 2.1044x; 2.1044x over previous
//
#include <hip/hip_runtime.h>
#include <hip/hip_bf16.h>
#include <cstdint>
#include <cstddef>

#define SLEN 2048
#define NHEAD 16
#define HDIM 64

typedef short bf16x8 __attribute__((ext_vector_type(8)));
typedef float f32x4 __attribute__((ext_vector_type(4)));

__device__ inline unsigned short f2bf(float f) {
  union { __hip_bfloat16 b; unsigned short u; } cv;
  cv.b = __float2bfloat16(f);
  return cv.u;
}

// ---------------------------------------------------------------------------
// GEMM1: qkv = x @ Wattn + bias  (M=rows, N=3072, K=1024), fp32 VALU.
// Epilogue: Q,K -> bf16 (bh,s,d); V -> bf16 TRANSPOSED (bh,d,s).
// ---------------------------------------------------------------------------
__global__ __launch_bounds__(256, 2) void qkv_gemm(
    const float* __restrict__ X, const float* __restrict__ W,
    const float* __restrict__ Bias,
    unsigned short* __restrict__ Qb, unsigned short* __restrict__ Kb,
    unsigned short* __restrict__ Vt, int m0)
{
  __shared__ float As[16][132];   // [k][m]
  __shared__ float Bs[16][132];   // [k][n]
  const int tid = threadIdx.x;
  const int tr = tid >> 4;
  const int tc = tid & 15;
  const int mtile = blockIdx.y * 128;
  const int nbase = blockIdx.x * 128;

  float acc[8][8];
  #pragma unroll
  for (int i = 0; i < 8; i++)
    #pragma unroll
    for (int j = 0; j < 8; j++) acc[i][j] = 0.f;

  float bias_[8];
  #pragma unroll
  for (int j = 0; j < 8; j++) bias_[j] = Bias[nbase + tc*8 + j];

  const int r_a = tid >> 2;
  const int c_a = (tid & 3) * 4;
  const int kk_b = tid >> 5;
  const int c_b = (tid & 31) * 4;

  for (int k0 = 0; k0 < 1024; k0 += 16) {
    #pragma unroll
    for (int ld = 0; ld < 2; ld++) {
      int r = r_a + ld*64;
      float4 a4 = *(const float4*)(X + (size_t)(m0 + mtile + r)*1024 + k0 + c_a);
      As[c_a+0][r] = a4.x; As[c_a+1][r] = a4.y;
      As[c_a+2][r] = a4.z; As[c_a+3][r] = a4.w;
    }
    #pragma unroll
    for (int ld = 0; ld < 2; ld++) {
      int kk = kk_b + ld*8;
      float4 b4 = *(const float4*)(W + (size_t)(k0 + kk)*3072 + nbase + c_b);
      *(float4*)&Bs[kk][c_b] = b4;
    }
    __syncthreads();
    #pragma unroll
    for (int kk = 0; kk < 16; kk++) {
      float4 a0 = *(const float4*)&As[kk][tr*8];
      float4 a1 = *(const float4*)&As[kk][tr*8+4];
      float4 b0 = *(const float4*)&Bs[kk][tc*8];
      float4 b1 = *(const float4*)&Bs[kk][tc*8+4];
      float av[8] = {a0.x,a0.y,a0.z,a0.w,a1.x,a1.y,a1.z,a1.w};
      float bv[8] = {b0.x,b0.y,b0.z,b0.w,b1.x,b1.y,b1.z,b1.w};
      #pragma unroll
      for (int i = 0; i < 8; i++)
        #pragma unroll
        for (int j = 0; j < 8; j++)
          acc[i][j] += av[i]*bv[j];
    }
    __syncthreads();
  }
  #pragma unroll
  for (int i = 0; i < 8; i++) {
    int lr = mtile + tr*8 + i;
    int bl = lr >> 11, s = lr & 2047;
    #pragma unroll
    for (int j4 = 0; j4 < 8; j4 += 4) {
      int n = nbase + tc*8 + j4;
      int which = n >> 10, rem = n & 1023;
      int h = rem >> 6, d = rem & 63;
      float v[4];
      #pragma unroll
      for (int jj = 0; jj < 4; jj++) v[jj] = acc[i][j4+jj] + bias_[j4+jj];
      int bhl = bl*16 + h;
      if (which == 2) {
        // V transposed: Vt[(bh*64 + d + jj)*2048 + s]
        #pragma unroll
        for (int jj = 0; jj < 4; jj++)
          Vt[((size_t)bhl*64 + d + jj)*SLEN + s] = f2bf(v[jj]);
      } else {
        unsigned short* base = (which == 0) ? Qb : Kb;
        ushort4 o4;
        o4.x = f2bf(v[0]); o4.y = f2bf(v[1]);
        o4.z = f2bf(v[2]); o4.w = f2bf(v[3]);
        *(ushort4*)(base + ((size_t)bhl*SLEN + s)*HDIM + d) = o4;
      }
    }
  }
}

// ---------------------------------------------------------------------------
// MFMA flash attention: block = 4 waves x 16 q-rows (64-row Q tile),
// 64-key K/V tiles in LDS (padded stride 72 -> 2-way bank aliasing only).
// mfma_f32_16x16x32_bf16; online softmax in registers; P through per-wave
// LDS to reshape into A-fragment layout. Output fp32 (bh,s,d).
// ---------------------------------------------------------------------------
__global__ __launch_bounds__(256, 2) void attn_mfma(
    const unsigned short* __restrict__ Qb, const unsigned short* __restrict__ Kb,
    const unsigned short* __restrict__ Vt, const float* __restrict__ mask,
    float* __restrict__ O, int b0)
{
  __shared__ unsigned short Qs[64][72];
  __shared__ unsigned short Ks[64][72];
  __shared__ unsigned short Vs[64][72];   // [d][key]
  __shared__ unsigned short Ps[4][16][72];

  const int tid = threadIdx.x;
  const int wid = tid >> 6, lane = tid & 63;
  const int lo = lane & 15, hi = lane >> 4;
  const int qt = blockIdx.x & 31;
  const int bh = blockIdx.x >> 5;
  const int bglob = b0 + (bh >> 4);
  const float* mrow = mask + (size_t)bglob * SLEN;

  const unsigned short* qg = Qb + ((size_t)bh*SLEN + qt*64)*HDIM;
  const unsigned short* kg = Kb + (size_t)bh*SLEN*HDIM;
  const unsigned short* vg = Vt + (size_t)bh*HDIM*SLEN;

  #pragma unroll
  for (int i = 0; i < 2; i++) {
    int idx = tid + i*256;
    int row = idx >> 3, d0 = (idx & 7)*8;
    *(bf16x8*)&Qs[row][d0] = *(const bf16x8*)(qg + (size_t)row*HDIM + d0);
  }
  __syncthreads();
  bf16x8 qa0 = *(const bf16x8*)&Qs[wid*16 + lo][8*hi];
  bf16x8 qa1 = *(const bf16x8*)&Qs[wid*16 + lo][32 + 8*hi];

  float m_[4], l_[4];
  f32x4 oacc[4];
  #pragma unroll
  for (int i = 0; i < 4; i++) { m_[i] = -INFINITY; l_[i] = 0.f; }
  #pragma unroll
  for (int i = 0; i < 4; i++) {
    f32x4 z = {0.f,0.f,0.f,0.f};
    oacc[i] = z;
  }

  for (int kt = 0; kt < SLEN/64; kt++) {
    __syncthreads();
    #pragma unroll
    for (int i = 0; i < 2; i++) {
      int idx = tid + i*256;
      int row = idx >> 3, d0 = (idx & 7)*8;
      *(bf16x8*)&Ks[row][d0] =
          *(const bf16x8*)(kg + (size_t)(kt*64 + row)*HDIM + d0);
      *(bf16x8*)&Vs[row][d0] =
          *(const bf16x8*)(vg + (size_t)row*SLEN + kt*64 + d0);
    }
    __syncthreads();

    // ---- S = Q K^T (per wave: 16 rows x 64 keys) ----
    f32x4 sacc[4];
    #pragma unroll
    for (int blk = 0; blk < 4; blk++) {
      bf16x8 kb0 = *(const bf16x8*)&Ks[blk*16 + lo][8*hi];
      bf16x8 kb1 = *(const bf16x8*)&Ks[blk*16 + lo][32 + 8*hi];
      f32x4 z = {0.f,0.f,0.f,0.f};
      z = __builtin_amdgcn_mfma_f32_16x16x32_bf16(qa0, kb0, z, 0, 0, 0);
      sacc[blk] = __builtin_amdgcn_mfma_f32_16x16x32_bf16(qa1, kb1, z, 0, 0, 0);
    }

    // ---- online softmax ----
    float mk[4];
    #pragma unroll
    for (int blk = 0; blk < 4; blk++) mk[blk] = mrow[kt*64 + blk*16 + lo];
    float s[4][4];
    float rmax[4] = {-INFINITY, -INFINITY, -INFINITY, -INFINITY};
    #pragma unroll
    for (int blk = 0; blk < 4; blk++)
      #pragma unroll
      for (int i = 0; i < 4; i++) {
        s[blk][i] = sacc[blk][i]*0.125f + mk[blk];
        rmax[i] = fmaxf(rmax[i], s[blk][i]);
      }
    #pragma unroll
    for (int i = 0; i < 4; i++) {
      rmax[i] = fmaxf(rmax[i], __shfl_xor(rmax[i], 1));
      rmax[i] = fmaxf(rmax[i], __shfl_xor(rmax[i], 2));
      rmax[i] = fmaxf(rmax[i], __shfl_xor(rmax[i], 4));
      rmax[i] = fmaxf(rmax[i], __shfl_xor(rmax[i], 8));
    }
    float corr[4], psum[4];
    #pragma unroll
    for (int i = 0; i < 4; i++) {
      float mnew = fmaxf(m_[i], rmax[i]);
      corr[i] = __expf(m_[i] - mnew);
      m_[i] = mnew;
      psum[i] = 0.f;
    }
    #pragma unroll
    for (int blk = 0; blk < 4; blk++)
      #pragma unroll
      for (int i = 0; i < 4; i++) {
        float p = __expf(s[blk][i] - m_[i]);
        psum[i] += p;
        Ps[wid][hi*4 + i][blk*16 + lo] = f2bf(p);
      }
    #pragma unroll
    for (int i = 0; i < 4; i++) {
      psum[i] += __shfl_xor(psum[i], 1);
      psum[i] += __shfl_xor(psum[i], 2);
      psum[i] += __shfl_xor(psum[i], 4);
      psum[i] += __shfl_xor(psum[i], 8);
      l_[i] = l_[i]*corr[i] + psum[i];
    }
    #pragma unroll
    for (int dblk = 0; dblk < 4; dblk++)
      #pragma unroll
      for (int i = 0; i < 4; i++)
        oacc[dblk][i] *= corr[i];

    // ---- O += P V (per-wave Ps; same-wave RAW, no barrier needed) ----
    bf16x8 pa0 = *(const bf16x8*)&Ps[wid][lo][8*hi];
    bf16x8 pa1 = *(const bf16x8*)&Ps[wid][lo][32 + 8*hi];
    #pragma unroll
    for (int dblk = 0; dblk < 4; dblk++) {
      bf16x8 vb0 = *(const bf16x8*)&Vs[dblk*16 + lo][8*hi];
      bf16x8 vb1 = *(const bf16x8*)&Vs[dblk*16 + lo][32 + 8*hi];
      oacc[dblk] = __builtin_amdgcn_mfma_f32_16x16x32_bf16(pa0, vb0, oacc[dblk], 0, 0, 0);
      oacc[dblk] = __builtin_amdgcn_mfma_f32_16x16x32_bf16(pa1, vb1, oacc[dblk], 0, 0, 0);
    }
  }

  const size_t obase = ((size_t)bh*SLEN + qt*64 + wid*16)*HDIM;
  #pragma unroll
  for (int i = 0; i < 4; i++) {
    float inv = 1.f / l_[i];
    int row = hi*4 + i;
    #pragma unroll
    for (int dblk = 0; dblk < 4; dblk++)
      O[obase + (size_t)row*HDIM + dblk*16 + lo] = oacc[dblk][i]*inv;
  }
}

// ---------------------------------------------------------------------------
// GEMM2: out = merge_heads(a) @ Wproj + bias  (fp32 VALU), A in (bh,s,d) f32.
// ---------------------------------------------------------------------------
__global__ __launch_bounds__(256, 2) void proj_gemm(
    const float* __restrict__ A, const float* __restrict__ W,
    const float* __restrict__ Bias,
    float* __restrict__ Out, int m0)
{
  __shared__ float As[16][132];
  __shared__ float Bs[16][132];
  const int tid = threadIdx.x;
  const int tr = tid >> 4, tc = tid & 15;
  const int mtile = blockIdx.y * 128;
  const int nbase = blockIdx.x * 128;

  float acc[8][8];
  #pragma unroll
  for (int i = 0; i < 8; i++)
    #pragma unroll
    for (int j = 0; j < 8; j++) acc[i][j] = 0.f;

  float bias_[8];
  #pragma unroll
  for (int j = 0; j < 8; j++) bias_[j] = Bias[nbase + tc*8 + j];

  const int r_a = tid >> 2;
  const int c_a = (tid & 3) * 4;
  const int kk_b = tid >> 5;
  const int c_b = (tid & 31) * 4;

  for (int k0 = 0; k0 < 1024; k0 += 16) {
    int h = k0 >> 6, dblk = k0 & 63;
    #pragma unroll
    for (int ld = 0; ld < 2; ld++) {
      int rr = r_a + ld*64;
      int lr = mtile + rr;
      int bl = lr >> 11, s = lr & 2047;
      float4 a4 = *(const float4*)(A + (((size_t)(bl*16 + h))*2048 + s)*64 + dblk + c_a);
      As[c_a+0][rr] = a4.x; As[c_a+1][rr] = a4.y;
      As[c_a+2][rr] = a4.z; As[c_a+3][rr] = a4.w;
    }
    #pragma unroll
    for (int ld = 0; ld < 2; ld++) {
      int kk = kk_b + ld*8;
      float4 b4 = *(const float4*)(W + (size_t)(k0 + kk)*1024 + nbase + c_b);
      *(float4*)&Bs[kk][c_b] = b4;
    }
    __syncthreads();
    #pragma unroll
    for (int kk = 0; kk < 16; kk++) {
      float4 a0 = *(const float4*)&As[kk][tr*8];
      float4 a1 = *(const float4*)&As[kk][tr*8+4];
      float4 b0 = *(const float4*)&Bs[kk][tc*8];
      float4 b1 = *(const float4*)&Bs[kk][tc*8+4];
      float av[8] = {a0.x,a0.y,a0.z,a0.w,a1.x,a1.y,a1.z,a1.w};
      float bv[8] = {b0.x,b0.y,b0.z,b0.w,b1.x,b1.y,b1.z,b1.w};
      #pragma unroll
      for (int i = 0; i < 8; i++)
        #pragma unroll
        for (int j = 0; j < 8; j++)
          acc[i][j] += av[i]*bv[j];
    }
    __syncthreads();
  }
  #pragma unroll
  for (int i = 0; i < 8; i++) {
    int lr = mtile + tr*8 + i;
    float* orow = Out + (size_t)(m0 + lr)*1024 + nbase + tc*8;
    #pragma unroll
    for (int j4 = 0; j4 < 8; j4 += 4) {
      float4 o;
      o.x = acc[i][j4+0] + bias_[j4+0];
      o.y = acc[i][j4+1] + bias_[j4+1];
      o.z = acc[i][j4+2] + bias_[j4+2];
      o.w = acc[i][j4+3] + bias_[j4+3];
      *(float4*)(orow + j4) = o;
    }
  }
}

extern "C" void kernel_launch(void* const* d_in, const int* in_sizes, int n_in,
                              void* d_out, int out_size, void* d_ws, size_t ws_size,
                              hipStream_t stream) {
  const float* x     = (const float*)d_in[0];
  const float* amask = (const float*)d_in[1];
  const float* wat   = (const float*)d_in[2];
  const float* bat   = (const float*)d_in[3];
  const float* wpr   = (const float*)d_in[4];
  const float* bpr   = (const float*)d_in[5];
  float* out = (float*)d_out;

  const size_t PB = (size_t)NHEAD * SLEN * HDIM;  // elems per batch per tensor
  // per-batch workspace: 3 bf16 tensors (Q,K,Vt) + 1 f32 (attn out) = 10 B/elem
  int bc;
  if (ws_size >= (size_t)4 * PB * 10)      bc = 4;
  else if (ws_size >= (size_t)2 * PB * 10) bc = 2;
  else                                     bc = 1;

  for (int b0 = 0; b0 < 4; b0 += bc) {
    unsigned short* Qb = (unsigned short*)d_ws;
    unsigned short* Kb = Qb + (size_t)bc * PB;
    unsigned short* Vt = Kb + (size_t)bc * PB;
    float* Of = (float*)(Vt + (size_t)bc * PB);
    int Mrows = bc * SLEN;
    dim3 g1(24, Mrows / 128);
    qkv_gemm<<<g1, dim3(256), 0, stream>>>(x, wat, bat, Qb, Kb, Vt, b0 * SLEN);
    attn_mfma<<<dim3(bc * NHEAD * (SLEN/64)), dim3(256), 0, stream>>>(
        Qb, Kb, Vt, amask, Of, b0);
    dim3 g2(8, Mrows / 128);
    proj_gemm<<<g2, dim3(256), 0, stream>>>(Of, wpr, bpr, out, b0 * SLEN);
  }
}

// Round 4
// 338.920 us; speedup vs baseline: 6.4885x; 3.0832x over previous
//
#include <hip/hip_runtime.h>
#include <hip/hip_bf16.h>
#include <cstdint>
#include <cstddef>

#define SLEN 2048
#define NHEAD 16
#define HDIM 64

typedef short bf16x8 __attribute__((ext_vector_type(8)));
typedef float f32x4 __attribute__((ext_vector_type(4)));

__device__ __forceinline__ unsigned short f2bf(float f) {
  union { __hip_bfloat16 b; unsigned short u; } cv;
  cv.b = __float2bfloat16(f);
  return cv.u;
}

__device__ __forceinline__ void async16(unsigned short* lds, const unsigned short* g) {
  __builtin_amdgcn_global_load_lds(
      (const __attribute__((address_space(1))) unsigned int*)g,
      (__attribute__((address_space(3))) unsigned int*)lds, 16, 0, 0);
}

// ---------------------------------------------------------------------------
// convert x (f32) -> bf16 flat
// ---------------------------------------------------------------------------
__global__ __launch_bounds__(256) void cvt_bf16(
    const float* __restrict__ in, unsigned short* __restrict__ out, int n8)
{
  int i = blockIdx.x * 256 + threadIdx.x;
  if (i >= n8) return;
  const float4 a = *(const float4*)(in + (size_t)i*8);
  const float4 b = *(const float4*)(in + (size_t)i*8 + 4);
  ushort4 o0 = {f2bf(a.x), f2bf(a.y), f2bf(a.z), f2bf(a.w)};
  ushort4 o1 = {f2bf(b.x), f2bf(b.y), f2bf(b.z), f2bf(b.w)};
  *(ushort4*)(out + (size_t)i*8)     = o0;
  *(ushort4*)(out + (size_t)i*8 + 4) = o1;
}

// ---------------------------------------------------------------------------
// transpose W (K,N) f32 -> Wt (N,K) bf16, 32x32 LDS tiles
// ---------------------------------------------------------------------------
__global__ __launch_bounds__(256) void transpose_w(
    const float* __restrict__ W, unsigned short* __restrict__ Wt, int K, int N)
{
  __shared__ unsigned short T[32][36];
  const int kb = blockIdx.y * 32, nb = blockIdx.x * 32;
  const int r = threadIdx.x >> 3, c4 = (threadIdx.x & 7) * 4;
  float4 w = *(const float4*)(W + (size_t)(kb + r)*N + nb + c4);
  T[c4+0][r] = f2bf(w.x); T[c4+1][r] = f2bf(w.y);
  T[c4+2][r] = f2bf(w.z); T[c4+3][r] = f2bf(w.w);
  __syncthreads();
  ushort4 o = {T[r][c4], T[r][c4+1], T[r][c4+2], T[r][c4+3]};
  *(ushort4*)(Wt + (size_t)(nb + r)*K + kb + c4) = o;
}

// ---------------------------------------------------------------------------
// GEMM1 (MFMA): qkv = xb @ WattnT^T + bias. M=bc*2048 rows, N=3072, K=1024.
// 128x128 tile, 4 waves (2x2), BK=32, global_load_lds staging, linear LDS.
// Epilogue: Q,K bf16 (bh,s,d); V bf16 transposed (bh,d,s) via LDS tile.
// ---------------------------------------------------------------------------
__global__ __launch_bounds__(256, 2) void gemm1_mfma(
    const unsigned short* __restrict__ Xb,    // (8192,1024) bf16
    const unsigned short* __restrict__ Wt,    // (3072,1024) bf16
    const float* __restrict__ Bias,           // (3072) f32
    unsigned short* __restrict__ Qb, unsigned short* __restrict__ Kb,
    unsigned short* __restrict__ Vt, int m0)
{
  __shared__ union {
    struct { unsigned short A[128*32]; unsigned short B[128*32]; } s;
    unsigned short vt[128*136];
  } u;
  const int tid = threadIdx.x;
  const int wid = tid >> 6, lane = tid & 63;
  const int lo = lane & 15, hi = lane >> 4;
  const int wr = wid >> 1, wc = wid & 1;
  const int mtile = blockIdx.y * 128;     // local row base within chunk
  const int nbase = blockIdx.x * 128;

  f32x4 acc[4][4];
  #pragma unroll
  for (int i = 0; i < 4; i++)
    #pragma unroll
    for (int j = 0; j < 4; j++) { f32x4 z = {0.f,0.f,0.f,0.f}; acc[i][j] = z; }

  const int ldrow = 32*wid + (lane >> 2);   // staging row (this wave, chunk 0)
  const int koff  = (lane & 3) * 8;         // bf16 elems within 32-k row

  const unsigned short* Abase = Xb + (size_t)(m0 + mtile)*1024;
  const unsigned short* Bbase = Wt + (size_t)nbase*1024;

  for (int k0 = 0; k0 < 1024; k0 += 32) {
    __syncthreads();
    #pragma unroll
    for (int cc = 0; cc < 2; cc++) {
      int r = ldrow + cc*16;
      async16(&u.s.A[r*32 + koff], Abase + (size_t)r*1024 + k0 + koff);
      async16(&u.s.B[r*32 + koff], Bbase + (size_t)r*1024 + k0 + koff);
    }
    __syncthreads();
    bf16x8 af[4], bf[4];
    #pragma unroll
    for (int mi = 0; mi < 4; mi++)
      af[mi] = *(const bf16x8*)&u.s.A[(wr*64 + mi*16 + lo)*32 + hi*8];
    #pragma unroll
    for (int ni = 0; ni < 4; ni++)
      bf[ni] = *(const bf16x8*)&u.s.B[(wc*64 + ni*16 + lo)*32 + hi*8];
    #pragma unroll
    for (int mi = 0; mi < 4; mi++)
      #pragma unroll
      for (int ni = 0; ni < 4; ni++)
        acc[mi][ni] = __builtin_amdgcn_mfma_f32_16x16x32_bf16(
            af[mi], bf[ni], acc[mi][ni], 0, 0, 0);
  }

  float bias_[4];
  #pragma unroll
  for (int ni = 0; ni < 4; ni++) bias_[ni] = Bias[nbase + wc*64 + ni*16 + lo];

  const int bl = mtile >> 11;           // local batch
  const int s0 = mtile & 2047;

  if (nbase < 2048) {
    unsigned short* dst = (nbase < 1024) ? Qb : Kb;
    const int nb2 = nbase & 1023;
    #pragma unroll
    for (int mi = 0; mi < 4; mi++)
      #pragma unroll
      for (int i = 0; i < 4; i++) {
        int s = s0 + wr*64 + mi*16 + hi*4 + i;
        #pragma unroll
        for (int ni = 0; ni < 4; ni++) {
          int n = nb2 + wc*64 + ni*16 + lo;
          int h = n >> 6, d = n & 63;
          dst[((size_t)(bl*16 + h)*SLEN + s)*HDIM + d] =
              f2bf(acc[mi][ni][i] + bias_[ni]);
        }
      }
  } else {
    __syncthreads();   // done reading u.s
    #pragma unroll
    for (int mi = 0; mi < 4; mi++)
      #pragma unroll
      for (int ni = 0; ni < 4; ni++)
        #pragma unroll
        for (int i = 0; i < 4; i++) {
          int ml = wr*64 + mi*16 + hi*4 + i;
          int nl = wc*64 + ni*16 + lo;
          u.vt[nl*136 + ml] = f2bf(acc[mi][ni][i] + bias_[ni]);
        }
    __syncthreads();
    const int rv = tid >> 1, halfc = (tid & 1)*64;
    const int ng = nbase - 2048 + rv;
    const int h = ng >> 6, d = ng & 63;
    unsigned short* drow = Vt + ((size_t)(bl*16 + h)*HDIM + d)*SLEN + s0 + halfc;
    #pragma unroll
    for (int j = 0; j < 8; j++) {   // FIX: was j<4 — only half the V columns copied
      bf16x8 v = *(const bf16x8*)&u.vt[rv*136 + halfc + j*8];
      *(bf16x8*)(drow + j*8) = v;
    }
  }
}

// ---------------------------------------------------------------------------
// MFMA flash attention, output bf16 (bh,s,d).
// ---------------------------------------------------------------------------
__global__ __launch_bounds__(256, 2) void attn_mfma(
    const unsigned short* __restrict__ Qb, const unsigned short* __restrict__ Kb,
    const unsigned short* __restrict__ Vt, const float* __restrict__ mask,
    unsigned short* __restrict__ O, int b0)
{
  __shared__ unsigned short Qs[64][72];
  __shared__ unsigned short Ks[64][72];
  __shared__ unsigned short Vs[64][72];   // [d][key]
  __shared__ unsigned short Ps[4][16][72];

  const int tid = threadIdx.x;
  const int wid = tid >> 6, lane = tid & 63;
  const int lo = lane & 15, hi = lane >> 4;
  const int qt = blockIdx.x & 31;
  const int bh = blockIdx.x >> 5;
  const int bglob = b0 + (bh >> 4);
  const float* mrow = mask + (size_t)bglob * SLEN;

  const unsigned short* qg = Qb + ((size_t)bh*SLEN + qt*64)*HDIM;
  const unsigned short* kg = Kb + (size_t)bh*SLEN*HDIM;
  const unsigned short* vg = Vt + (size_t)bh*HDIM*SLEN;

  #pragma unroll
  for (int i = 0; i < 2; i++) {
    int idx = tid + i*256;
    int row = idx >> 3, d0 = (idx & 7)*8;
    *(bf16x8*)&Qs[row][d0] = *(const bf16x8*)(qg + (size_t)row*HDIM + d0);
  }
  __syncthreads();
  bf16x8 qa0 = *(const bf16x8*)&Qs[wid*16 + lo][8*hi];
  bf16x8 qa1 = *(const bf16x8*)&Qs[wid*16 + lo][32 + 8*hi];

  float m_[4], l_[4];
  f32x4 oacc[4];
  #pragma unroll
  for (int i = 0; i < 4; i++) { m_[i] = -INFINITY; l_[i] = 0.f; }
  #pragma unroll
  for (int i = 0; i < 4; i++) { f32x4 z = {0.f,0.f,0.f,0.f}; oacc[i] = z; }

  for (int kt = 0; kt < SLEN/64; kt++) {
    __syncthreads();
    #pragma unroll
    for (int i = 0; i < 2; i++) {
      int idx = tid + i*256;
      int row = idx >> 3, d0 = (idx & 7)*8;
      *(bf16x8*)&Ks[row][d0] =
          *(const bf16x8*)(kg + (size_t)(kt*64 + row)*HDIM + d0);
      *(bf16x8*)&Vs[row][d0] =
          *(const bf16x8*)(vg + (size_t)row*SLEN + kt*64 + d0);
    }
    __syncthreads();

    f32x4 sacc[4];
    #pragma unroll
    for (int blk = 0; blk < 4; blk++) {
      bf16x8 kb0 = *(const bf16x8*)&Ks[blk*16 + lo][8*hi];
      bf16x8 kb1 = *(const bf16x8*)&Ks[blk*16 + lo][32 + 8*hi];
      f32x4 z = {0.f,0.f,0.f,0.f};
      z = __builtin_amdgcn_mfma_f32_16x16x32_bf16(qa0, kb0, z, 0, 0, 0);
      sacc[blk] = __builtin_amdgcn_mfma_f32_16x16x32_bf16(qa1, kb1, z, 0, 0, 0);
    }

    float mk[4];
    #pragma unroll
    for (int blk = 0; blk < 4; blk++) mk[blk] = mrow[kt*64 + blk*16 + lo];
    float s[4][4];
    float rmax[4] = {-INFINITY, -INFINITY, -INFINITY, -INFINITY};
    #pragma unroll
    for (int blk = 0; blk < 4; blk++)
      #pragma unroll
      for (int i = 0; i < 4; i++) {
        s[blk][i] = sacc[blk][i]*0.125f + mk[blk];
        rmax[i] = fmaxf(rmax[i], s[blk][i]);
      }
    #pragma unroll
    for (int i = 0; i < 4; i++) {
      rmax[i] = fmaxf(rmax[i], __shfl_xor(rmax[i], 1));
      rmax[i] = fmaxf(rmax[i], __shfl_xor(rmax[i], 2));
      rmax[i] = fmaxf(rmax[i], __shfl_xor(rmax[i], 4));
      rmax[i] = fmaxf(rmax[i], __shfl_xor(rmax[i], 8));
    }
    float corr[4], psum[4];
    #pragma unroll
    for (int i = 0; i < 4; i++) {
      float mnew = fmaxf(m_[i], rmax[i]);
      corr[i] = __expf(m_[i] - mnew);
      m_[i] = mnew;
      psum[i] = 0.f;
    }
    #pragma unroll
    for (int blk = 0; blk < 4; blk++)
      #pragma unroll
      for (int i = 0; i < 4; i++) {
        float p = __expf(s[blk][i] - m_[i]);
        psum[i] += p;
        Ps[wid][hi*4 + i][blk*16 + lo] = f2bf(p);
      }
    #pragma unroll
    for (int i = 0; i < 4; i++) {
      psum[i] += __shfl_xor(psum[i], 1);
      psum[i] += __shfl_xor(psum[i], 2);
      psum[i] += __shfl_xor(psum[i], 4);
      psum[i] += __shfl_xor(psum[i], 8);
      l_[i] = l_[i]*corr[i] + psum[i];
    }
    #pragma unroll
    for (int dblk = 0; dblk < 4; dblk++)
      #pragma unroll
      for (int i = 0; i < 4; i++)
        oacc[dblk][i] *= corr[i];

    bf16x8 pa0 = *(const bf16x8*)&Ps[wid][lo][8*hi];
    bf16x8 pa1 = *(const bf16x8*)&Ps[wid][lo][32 + 8*hi];
    #pragma unroll
    for (int dblk = 0; dblk < 4; dblk++) {
      bf16x8 vb0 = *(const bf16x8*)&Vs[dblk*16 + lo][8*hi];
      bf16x8 vb1 = *(const bf16x8*)&Vs[dblk*16 + lo][32 + 8*hi];
      oacc[dblk] = __builtin_amdgcn_mfma_f32_16x16x32_bf16(pa0, vb0, oacc[dblk], 0, 0, 0);
      oacc[dblk] = __builtin_amdgcn_mfma_f32_16x16x32_bf16(pa1, vb1, oacc[dblk], 0, 0, 0);
    }
  }

  const size_t obase = ((size_t)bh*SLEN + qt*64 + wid*16)*HDIM;
  #pragma unroll
  for (int i = 0; i < 4; i++) {
    float inv = 1.f / l_[i];
    int row = hi*4 + i;
    #pragma unroll
    for (int dblk = 0; dblk < 4; dblk++)
      O[obase + (size_t)row*HDIM + dblk*16 + lo] = f2bf(oacc[dblk][i]*inv);
  }
}

// ---------------------------------------------------------------------------
// GEMM2 (MFMA): out = merge_heads(Ob) @ WprojT^T + bias. N=1024, K=1024.
// ---------------------------------------------------------------------------
__global__ __launch_bounds__(256, 2) void gemm2_mfma(
    const unsigned short* __restrict__ Ob,    // (bc*16,2048,64) bf16
    const unsigned short* __restrict__ Wt,    // (1024,1024) bf16
    const float* __restrict__ Bias,
    float* __restrict__ Out, int m0)
{
  __shared__ unsigned short As[128*32];
  __shared__ unsigned short Bs[128*32];
  const int tid = threadIdx.x;
  const int wid = tid >> 6, lane = tid & 63;
  const int lo = lane & 15, hi = lane >> 4;
  const int wr = wid >> 1, wc = wid & 1;
  const int mtile = blockIdx.y * 128;
  const int nbase = blockIdx.x * 128;

  f32x4 acc[4][4];
  #pragma unroll
  for (int i = 0; i < 4; i++)
    #pragma unroll
    for (int j = 0; j < 4; j++) { f32x4 z = {0.f,0.f,0.f,0.f}; acc[i][j] = z; }

  const int ldrow = 32*wid + (lane >> 2);
  const int koff  = (lane & 3) * 8;

  const int bl = mtile >> 11;
  const int s0 = mtile & 2047;
  const unsigned short* Bbase = Wt + (size_t)nbase*1024;

  for (int k0 = 0; k0 < 1024; k0 += 32) {
    const int h = k0 >> 6;
    const int dpart = (k0 & 63) + koff;
    __syncthreads();
    #pragma unroll
    for (int cc = 0; cc < 2; cc++) {
      int r = ldrow + cc*16;
      const unsigned short* ga =
          Ob + ((size_t)(bl*16 + h)*SLEN + s0 + r)*HDIM + dpart;
      async16(&As[r*32 + koff], ga);
      async16(&Bs[r*32 + koff], Bbase + (size_t)r*1024 + k0 + koff);
    }
    __syncthreads();
    bf16x8 af[4], bf[4];
    #pragma unroll
    for (int mi = 0; mi < 4; mi++)
      af[mi] = *(const bf16x8*)&As[(wr*64 + mi*16 + lo)*32 + hi*8];
    #pragma unroll
    for (int ni = 0; ni < 4; ni++)
      bf[ni] = *(const bf16x8*)&Bs[(wc*64 + ni*16 + lo)*32 + hi*8];
    #pragma unroll
    for (int mi = 0; mi < 4; mi++)
      #pragma unroll
      for (int ni = 0; ni < 4; ni++)
        acc[mi][ni] = __builtin_amdgcn_mfma_f32_16x16x32_bf16(
            af[mi], bf[ni], acc[mi][ni], 0, 0, 0);
  }

  float bias_[4];
  #pragma unroll
  for (int ni = 0; ni < 4; ni++) bias_[ni] = Bias[nbase + wc*64 + ni*16 + lo];

  #pragma unroll
  for (int mi = 0; mi < 4; mi++)
    #pragma unroll
    for (int i = 0; i < 4; i++) {
      int m = m0 + mtile + wr*64 + mi*16 + hi*4 + i;
      float* orow = Out + (size_t)m*1024 + nbase + wc*64 + lo;
      #pragma unroll
      for (int ni = 0; ni < 4; ni++)
        orow[ni*16] = acc[mi][ni][i] + bias_[ni];
    }
}

extern "C" void kernel_launch(void* const* d_in, const int* in_sizes, int n_in,
                              void* d_out, int out_size, void* d_ws, size_t ws_size,
                              hipStream_t stream) {
  const float* x     = (const float*)d_in[0];
  const float* amask = (const float*)d_in[1];
  const float* wat   = (const float*)d_in[2];
  const float* bat   = (const float*)d_in[3];
  const float* wpr   = (const float*)d_in[4];
  const float* bpr   = (const float*)d_in[5];
  float* out = (float*)d_out;

  unsigned short* WattnT = (unsigned short*)d_ws;
  unsigned short* WprojT = WattnT + (size_t)3072*1024;
  unsigned short* xb     = WprojT + (size_t)1024*1024;
  unsigned short* chunk0 = xb + (size_t)8192*1024;

  const size_t PB = (size_t)NHEAD * SLEN * HDIM;       // 2M elems / batch / tensor
  const size_t base_bytes = ((size_t)3072*1024 + (size_t)1024*1024 + (size_t)8192*1024) * 2;
  int bc = 1;
  if (ws_size >= base_bytes + 4 * 4 * PB * 2)      bc = 4;
  else if (ws_size >= base_bytes + 2 * 4 * PB * 2) bc = 2;

  // one-time converts
  cvt_bf16<<<dim3((8192*1024/8 + 255)/256), dim3(256), 0, stream>>>(
      x, xb, 8192*1024/8);
  transpose_w<<<dim3(3072/32, 1024/32), dim3(256), 0, stream>>>(wat, WattnT, 1024, 3072);
  transpose_w<<<dim3(1024/32, 1024/32), dim3(256), 0, stream>>>(wpr, WprojT, 1024, 1024);

  for (int b0 = 0; b0 < 4; b0 += bc) {
    unsigned short* Qb = chunk0;
    unsigned short* Kb = Qb + (size_t)bc * PB;
    unsigned short* Vt = Kb + (size_t)bc * PB;
    unsigned short* Ob = Vt + (size_t)bc * PB;
    int Mrows = bc * SLEN;
    gemm1_mfma<<<dim3(24, Mrows/128), dim3(256), 0, stream>>>(
        xb, WattnT, bat, Qb, Kb, Vt, b0 * SLEN);
    attn_mfma<<<dim3(bc * NHEAD * (SLEN/64)), dim3(256), 0, stream>>>(
        Qb, Kb, Vt, amask, Ob, b0);
    gemm2_mfma<<<dim3(8, Mrows/128), dim3(256), 0, stream>>>(
        Ob, WprojT, bpr, out, b0 * SLEN);
  }
}

// Round 5
// 295.169 us; speedup vs baseline: 7.4503x; 1.1482x over previous
//
#include <hip/hip_runtime.h>
#include <hip/hip_bf16.h>
#include <cstdint>
#include <cstddef>

#define SLEN 2048
#define NHEAD 16
#define HDIM 64

typedef short bf16x8 __attribute__((ext_vector_type(8)));
typedef float f32x4 __attribute__((ext_vector_type(4)));

__device__ __forceinline__ unsigned short f2bf(float f) {
  union { __hip_bfloat16 b; unsigned short u; } cv;
  cv.b = __float2bfloat16(f);
  return cv.u;
}

__device__ __forceinline__ unsigned pack2bf(float a, float b) {
  return (unsigned)f2bf(a) | ((unsigned)f2bf(b) << 16);
}

__device__ __forceinline__ void async16(unsigned short* lds, const unsigned short* g) {
  __builtin_amdgcn_global_load_lds(
      (const __attribute__((address_space(1))) unsigned int*)g,
      (__attribute__((address_space(3))) unsigned int*)lds, 16, 0, 0);
}

// ---------------------------------------------------------------------------
// convert x (f32) -> bf16 flat
// ---------------------------------------------------------------------------
__global__ __launch_bounds__(256) void cvt_bf16(
    const float* __restrict__ in, unsigned short* __restrict__ out, int n8)
{
  int i = blockIdx.x * 256 + threadIdx.x;
  if (i >= n8) return;
  const float4 a = *(const float4*)(in + (size_t)i*8);
  const float4 b = *(const float4*)(in + (size_t)i*8 + 4);
  ushort4 o0 = {f2bf(a.x), f2bf(a.y), f2bf(a.z), f2bf(a.w)};
  ushort4 o1 = {f2bf(b.x), f2bf(b.y), f2bf(b.z), f2bf(b.w)};
  *(ushort4*)(out + (size_t)i*8)     = o0;
  *(ushort4*)(out + (size_t)i*8 + 4) = o1;
}

// ---------------------------------------------------------------------------
// mask (f32) -> mask * log2(e)  (so softmax runs in exp2 domain)
// ---------------------------------------------------------------------------
__global__ __launch_bounds__(256) void scale_mask(
    const float* __restrict__ in, float* __restrict__ out, int n)
{
  int i = blockIdx.x * 256 + threadIdx.x;
  if (i < n) out[i] = in[i] * 1.44269504088896f;
}

// ---------------------------------------------------------------------------
// transpose W (K,N) f32 -> Wt (N,K) bf16, 32x32 LDS tiles
// ---------------------------------------------------------------------------
__global__ __launch_bounds__(256) void transpose_w(
    const float* __restrict__ W, unsigned short* __restrict__ Wt, int K, int N)
{
  __shared__ unsigned short T[32][36];
  const int kb = blockIdx.y * 32, nb = blockIdx.x * 32;
  const int r = threadIdx.x >> 3, c4 = (threadIdx.x & 7) * 4;
  float4 w = *(const float4*)(W + (size_t)(kb + r)*N + nb + c4);
  T[c4+0][r] = f2bf(w.x); T[c4+1][r] = f2bf(w.y);
  T[c4+2][r] = f2bf(w.z); T[c4+3][r] = f2bf(w.w);
  __syncthreads();
  ushort4 o = {T[r][c4], T[r][c4+1], T[r][c4+2], T[r][c4+3]};
  *(ushort4*)(Wt + (size_t)(nb + r)*K + kb + c4) = o;
}

// ---------------------------------------------------------------------------
// GEMM1 (MFMA): qkv = xb @ WattnT^T + bias. (unchanged from round 4)
// ---------------------------------------------------------------------------
__global__ __launch_bounds__(256, 2) void gemm1_mfma(
    const unsigned short* __restrict__ Xb,
    const unsigned short* __restrict__ Wt,
    const float* __restrict__ Bias,
    unsigned short* __restrict__ Qb, unsigned short* __restrict__ Kb,
    unsigned short* __restrict__ Vt, int m0)
{
  __shared__ union {
    struct { unsigned short A[128*32]; unsigned short B[128*32]; } s;
    unsigned short vt[128*136];
  } u;
  const int tid = threadIdx.x;
  const int wid = tid >> 6, lane = tid & 63;
  const int lo = lane & 15, hi = lane >> 4;
  const int wr = wid >> 1, wc = wid & 1;
  const int mtile = blockIdx.y * 128;
  const int nbase = blockIdx.x * 128;

  f32x4 acc[4][4];
  #pragma unroll
  for (int i = 0; i < 4; i++)
    #pragma unroll
    for (int j = 0; j < 4; j++) { f32x4 z = {0.f,0.f,0.f,0.f}; acc[i][j] = z; }

  const int ldrow = 32*wid + (lane >> 2);
  const int koff  = (lane & 3) * 8;

  const unsigned short* Abase = Xb + (size_t)(m0 + mtile)*1024;
  const unsigned short* Bbase = Wt + (size_t)nbase*1024;

  for (int k0 = 0; k0 < 1024; k0 += 32) {
    __syncthreads();
    #pragma unroll
    for (int cc = 0; cc < 2; cc++) {
      int r = ldrow + cc*16;
      async16(&u.s.A[r*32 + koff], Abase + (size_t)r*1024 + k0 + koff);
      async16(&u.s.B[r*32 + koff], Bbase + (size_t)r*1024 + k0 + koff);
    }
    __syncthreads();
    bf16x8 af[4], bf[4];
    #pragma unroll
    for (int mi = 0; mi < 4; mi++)
      af[mi] = *(const bf16x8*)&u.s.A[(wr*64 + mi*16 + lo)*32 + hi*8];
    #pragma unroll
    for (int ni = 0; ni < 4; ni++)
      bf[ni] = *(const bf16x8*)&u.s.B[(wc*64 + ni*16 + lo)*32 + hi*8];
    #pragma unroll
    for (int mi = 0; mi < 4; mi++)
      #pragma unroll
      for (int ni = 0; ni < 4; ni++)
        acc[mi][ni] = __builtin_amdgcn_mfma_f32_16x16x32_bf16(
            af[mi], bf[ni], acc[mi][ni], 0, 0, 0);
  }

  float bias_[4];
  #pragma unroll
  for (int ni = 0; ni < 4; ni++) bias_[ni] = Bias[nbase + wc*64 + ni*16 + lo];

  const int bl = mtile >> 11;
  const int s0 = mtile & 2047;

  if (nbase < 2048) {
    unsigned short* dst = (nbase < 1024) ? Qb : Kb;
    const int nb2 = nbase & 1023;
    #pragma unroll
    for (int mi = 0; mi < 4; mi++)
      #pragma unroll
      for (int i = 0; i < 4; i++) {
        int s = s0 + wr*64 + mi*16 + hi*4 + i;
        #pragma unroll
        for (int ni = 0; ni < 4; ni++) {
          int n = nb2 + wc*64 + ni*16 + lo;
          int h = n >> 6, d = n & 63;
          dst[((size_t)(bl*16 + h)*SLEN + s)*HDIM + d] =
              f2bf(acc[mi][ni][i] + bias_[ni]);
        }
      }
  } else {
    __syncthreads();
    #pragma unroll
    for (int mi = 0; mi < 4; mi++)
      #pragma unroll
      for (int ni = 0; ni < 4; ni++)
        #pragma unroll
        for (int i = 0; i < 4; i++) {
          int ml = wr*64 + mi*16 + hi*4 + i;
          int nl = wc*64 + ni*16 + lo;
          u.vt[nl*136 + ml] = f2bf(acc[mi][ni][i] + bias_[ni]);
        }
    __syncthreads();
    const int rv = tid >> 1, halfc = (tid & 1)*64;
    const int ng = nbase - 2048 + rv;
    const int h = ng >> 6, d = ng & 63;
    unsigned short* drow = Vt + ((size_t)(bl*16 + h)*HDIM + d)*SLEN + s0 + halfc;
    #pragma unroll
    for (int j = 0; j < 8; j++) {
      bf16x8 v = *(const bf16x8*)&u.vt[rv*136 + halfc + j*8];
      *(bf16x8*)(drow + j*8) = v;
    }
  }
}

// ---------------------------------------------------------------------------
// MFMA flash attention v2: swapped QK^T (lane owns one q-row's scores),
// exp2-domain softmax with prescaled mask, defer-max (THR=8), double-buffered
// K/V via global_load_lds with pre-swizzled source chunks, no Q LDS.
// Output bf16 (bh,s,d).
// ---------------------------------------------------------------------------
__global__ __launch_bounds__(256, 2) void attn_mfma(
    const unsigned short* __restrict__ Qb, const unsigned short* __restrict__ Kb,
    const unsigned short* __restrict__ Vt, const float* __restrict__ maskL,
    unsigned short* __restrict__ O, int b0)
{
  __shared__ unsigned short Ks[2][64*64];   // [buf][row*64 + chunk^(row&7) swizzled]
  __shared__ unsigned short Vs[2][64*64];   // [buf][d-row][key chunks, swizzled]
  __shared__ unsigned short Ps[4][16][68];  // [wave][q-row][key] (padded)

  const int tid = threadIdx.x;
  const int wid = tid >> 6, lane = tid & 63;
  const int lo = lane & 15, hi = lane >> 4;
  const int qt = blockIdx.x & 31;
  const int bh = blockIdx.x >> 5;
  const int bglob = b0 + (bh >> 4);
  const float* mrow = maskL + (size_t)bglob * SLEN;

  const unsigned short* qg = Qb + ((size_t)bh*SLEN + qt*64)*HDIM;
  const unsigned short* kg = Kb + (size_t)bh*SLEN*HDIM;
  const unsigned short* vg = Vt + (size_t)bh*HDIM*SLEN;

  // Q fragments straight from global (read once): B-operand rows = q (lane lo)
  const unsigned short* qrow = qg + (size_t)(wid*16 + lo)*HDIM;
  const bf16x8 qa0 = *(const bf16x8*)(qrow + hi*8);
  const bf16x8 qa1 = *(const bf16x8*)(qrow + 32 + hi*8);

  // staging: linear LDS dest (lane*16B), XOR-swizzled global source chunk
  auto STAGE = [&](int bu, int kt2) {
    #pragma unroll
    for (int i = 0; i < 2; i++) {
      int slot = tid + i*256;
      int row = slot >> 3, p = slot & 7;
      int c = p ^ (row & 7);
      async16(&Ks[bu][row*64 + p*8], kg + (size_t)(kt2*64 + row)*HDIM + c*8);
      async16(&Vs[bu][row*64 + p*8], vg + (size_t)row*SLEN + kt2*64 + c*8);
    }
  };

  float m_ = -INFINITY, l_ = 0.f;   // per-lane state for q-row lo (x4 replicated)
  f32x4 oacc[4];
  #pragma unroll
  for (int i = 0; i < 4; i++) { f32x4 z = {0.f,0.f,0.f,0.f}; oacc[i] = z; }

  const float SC2 = 0.125f * 1.44269504088896f;   // scale * log2(e)
  const int x7 = lo & 7;

  STAGE(0, 0);
  for (int kt = 0; kt < SLEN/64; kt++) {
    const int cur = kt & 1;
    __syncthreads();                      // drains async stage of buf[cur]
    if (kt + 1 < SLEN/64) STAGE(cur ^ 1, kt + 1);   // latency hides under compute

    // ---- S^T = K Q^T : lane holds 16 scores for q-row lo ----
    f32x4 sacc[4];
    #pragma unroll
    for (int blk = 0; blk < 4; blk++) {
      const int row = blk*16 + lo;
      bf16x8 kb0 = *(const bf16x8*)&Ks[cur][row*64 + ((hi     ^ x7)*8)];
      bf16x8 kb1 = *(const bf16x8*)&Ks[cur][row*64 + (((hi+4) ^ x7)*8)];
      f32x4 z = {0.f,0.f,0.f,0.f};
      z = __builtin_amdgcn_mfma_f32_16x16x32_bf16(kb0, qa0, z, 0, 0, 0);
      sacc[blk] = __builtin_amdgcn_mfma_f32_16x16x32_bf16(kb1, qa1, z, 0, 0, 0);
    }

    // ---- softmax in exp2 domain ----
    float sl[4][4];
    float rmax = -INFINITY;
    #pragma unroll
    for (int blk = 0; blk < 4; blk++) {
      float4 mk = *(const float4*)(mrow + kt*64 + blk*16 + hi*4);
      sl[blk][0] = fmaf(sacc[blk][0], SC2, mk.x);
      sl[blk][1] = fmaf(sacc[blk][1], SC2, mk.y);
      sl[blk][2] = fmaf(sacc[blk][2], SC2, mk.z);
      sl[blk][3] = fmaf(sacc[blk][3], SC2, mk.w);
      #pragma unroll
      for (int i = 0; i < 4; i++) rmax = fmaxf(rmax, sl[blk][i]);
    }
    rmax = fmaxf(rmax, __shfl_xor(rmax, 16));
    rmax = fmaxf(rmax, __shfl_xor(rmax, 32));

    if (!__all(rmax <= m_ + 8.f)) {       // defer-max: rescale only when needed
      float mnew = fmaxf(m_, rmax);
      float corr = exp2f(m_ - mnew);      // -inf first iter -> 0
      m_ = mnew;
      l_ *= corr;
      float c4[4];
      #pragma unroll
      for (int i = 0; i < 4; i++) c4[i] = __shfl(corr, hi*4 + i);
      #pragma unroll
      for (int dblk = 0; dblk < 4; dblk++)
        #pragma unroll
        for (int i = 0; i < 4; i++) oacc[dblk][i] *= c4[i];
    }

    float psum = 0.f;
    #pragma unroll
    for (int blk = 0; blk < 4; blk++) {
      #pragma unroll
      for (int t = 0; t < 2; t++) {
        float p0 = exp2f(sl[blk][2*t]   - m_);
        float p1 = exp2f(sl[blk][2*t+1] - m_);
        psum += p0 + p1;
        *(unsigned*)&Ps[wid][lo][blk*16 + hi*4 + 2*t] = pack2bf(p0, p1);
      }
    }
    psum += __shfl_xor(psum, 16);
    psum += __shfl_xor(psum, 32);
    l_ += psum;

    // ---- O += P V (Ps same-wave RAW) ----
    bf16x8 pa0 = *(const bf16x8*)&Ps[wid][lo][hi*8];
    bf16x8 pa1 = *(const bf16x8*)&Ps[wid][lo][32 + hi*8];
    #pragma unroll
    for (int dblk = 0; dblk < 4; dblk++) {
      const int row = dblk*16 + lo;
      bf16x8 vb0 = *(const bf16x8*)&Vs[cur][row*64 + ((hi     ^ x7)*8)];
      bf16x8 vb1 = *(const bf16x8*)&Vs[cur][row*64 + (((hi+4) ^ x7)*8)];
      oacc[dblk] = __builtin_amdgcn_mfma_f32_16x16x32_bf16(pa0, vb0, oacc[dblk], 0, 0, 0);
      oacc[dblk] = __builtin_amdgcn_mfma_f32_16x16x32_bf16(pa1, vb1, oacc[dblk], 0, 0, 0);
    }
  }

  float invl = 1.f / l_;
  float inv4[4];
  #pragma unroll
  for (int i = 0; i < 4; i++) inv4[i] = __shfl(invl, hi*4 + i);

  const size_t obase = ((size_t)bh*SLEN + qt*64 + wid*16)*HDIM;
  #pragma unroll
  for (int i = 0; i < 4; i++) {
    int row = hi*4 + i;
    #pragma unroll
    for (int dblk = 0; dblk < 4; dblk++)
      O[obase + (size_t)row*HDIM + dblk*16 + lo] = f2bf(oacc[dblk][i]*inv4[i]);
  }
}

// ---------------------------------------------------------------------------
// GEMM2 (MFMA): out = merge_heads(Ob) @ WprojT^T + bias. (unchanged)
// ---------------------------------------------------------------------------
__global__ __launch_bounds__(256, 2) void gemm2_mfma(
    const unsigned short* __restrict__ Ob,
    const unsigned short* __restrict__ Wt,
    const float* __restrict__ Bias,
    float* __restrict__ Out, int m0)
{
  __shared__ unsigned short As[128*32];
  __shared__ unsigned short Bs[128*32];
  const int tid = threadIdx.x;
  const int wid = tid >> 6, lane = tid & 63;
  const int lo = lane & 15, hi = lane >> 4;
  const int wr = wid >> 1, wc = wid & 1;
  const int mtile = blockIdx.y * 128;
  const int nbase = blockIdx.x * 128;

  f32x4 acc[4][4];
  #pragma unroll
  for (int i = 0; i < 4; i++)
    #pragma unroll
    for (int j = 0; j < 4; j++) { f32x4 z = {0.f,0.f,0.f,0.f}; acc[i][j] = z; }

  const int ldrow = 32*wid + (lane >> 2);
  const int koff  = (lane & 3) * 8;

  const int bl = mtile >> 11;
  const int s0 = mtile & 2047;
  const unsigned short* Bbase = Wt + (size_t)nbase*1024;

  for (int k0 = 0; k0 < 1024; k0 += 32) {
    const int h = k0 >> 6;
    const int dpart = (k0 & 63) + koff;
    __syncthreads();
    #pragma unroll
    for (int cc = 0; cc < 2; cc++) {
      int r = ldrow + cc*16;
      const unsigned short* ga =
          Ob + ((size_t)(bl*16 + h)*SLEN + s0 + r)*HDIM + dpart;
      async16(&As[r*32 + koff], ga);
      async16(&Bs[r*32 + koff], Bbase + (size_t)r*1024 + k0 + koff);
    }
    __syncthreads();
    bf16x8 af[4], bf[4];
    #pragma unroll
    for (int mi = 0; mi < 4; mi++)
      af[mi] = *(const bf16x8*)&As[(wr*64 + mi*16 + lo)*32 + hi*8];
    #pragma unroll
    for (int ni = 0; ni < 4; ni++)
      bf[ni] = *(const bf16x8*)&Bs[(wc*64 + ni*16 + lo)*32 + hi*8];
    #pragma unroll
    for (int mi = 0; mi < 4; mi++)
      #pragma unroll
      for (int ni = 0; ni < 4; ni++)
        acc[mi][ni] = __builtin_amdgcn_mfma_f32_16x16x32_bf16(
            af[mi], bf[ni], acc[mi][ni], 0, 0, 0);
  }

  float bias_[4];
  #pragma unroll
  for (int ni = 0; ni < 4; ni++) bias_[ni] = Bias[nbase + wc*64 + ni*16 + lo];

  #pragma unroll
  for (int mi = 0; mi < 4; mi++)
    #pragma unroll
    for (int i = 0; i < 4; i++) {
      int m = m0 + mtile + wr*64 + mi*16 + hi*4 + i;
      float* orow = Out + (size_t)m*1024 + nbase + wc*64 + lo;
      #pragma unroll
      for (int ni = 0; ni < 4; ni++)
        orow[ni*16] = acc[mi][ni][i] + bias_[ni];
    }
}

extern "C" void kernel_launch(void* const* d_in, const int* in_sizes, int n_in,
                              void* d_out, int out_size, void* d_ws, size_t ws_size,
                              hipStream_t stream) {
  const float* x     = (const float*)d_in[0];
  const float* amask = (const float*)d_in[1];
  const float* wat   = (const float*)d_in[2];
  const float* bat   = (const float*)d_in[3];
  const float* wpr   = (const float*)d_in[4];
  const float* bpr   = (const float*)d_in[5];
  float* out = (float*)d_out;

  unsigned short* WattnT = (unsigned short*)d_ws;
  unsigned short* WprojT = WattnT + (size_t)3072*1024;
  unsigned short* xb     = WprojT + (size_t)1024*1024;
  float*          maskL  = (float*)(xb + (size_t)8192*1024);
  unsigned short* chunk0 = (unsigned short*)(maskL + 4*SLEN);

  const size_t PB = (size_t)NHEAD * SLEN * HDIM;
  const size_t base_bytes = ((size_t)3072*1024 + (size_t)1024*1024 + (size_t)8192*1024) * 2
                          + (size_t)4*SLEN*4;
  int bc = 1;
  if (ws_size >= base_bytes + 4 * 4 * PB * 2)      bc = 4;
  else if (ws_size >= base_bytes + 2 * 4 * PB * 2) bc = 2;

  cvt_bf16<<<dim3((8192*1024/8 + 255)/256), dim3(256), 0, stream>>>(
      x, xb, 8192*1024/8);
  scale_mask<<<dim3((4*SLEN + 255)/256), dim3(256), 0, stream>>>(
      amask, maskL, 4*SLEN);
  transpose_w<<<dim3(3072/32, 1024/32), dim3(256), 0, stream>>>(wat, WattnT, 1024, 3072);
  transpose_w<<<dim3(1024/32, 1024/32), dim3(256), 0, stream>>>(wpr, WprojT, 1024, 1024);

  for (int b0 = 0; b0 < 4; b0 += bc) {
    unsigned short* Qb = chunk0;
    unsigned short* Kb = Qb + (size_t)bc * PB;
    unsigned short* Vt = Kb + (size_t)bc * PB;
    unsigned short* Ob = Vt + (size_t)bc * PB;
    int Mrows = bc * SLEN;
    gemm1_mfma<<<dim3(24, Mrows/128), dim3(256), 0, stream>>>(
        xb, WattnT, bat, Qb, Kb, Vt, b0 * SLEN);
    attn_mfma<<<dim3(bc * NHEAD * (SLEN/64)), dim3(256), 0, stream>>>(
        Qb, Kb, Vt, maskL, Ob, b0);
    gemm2_mfma<<<dim3(8, Mrows/128), dim3(256), 0, stream>>>(
        Ob, WprojT, bpr, out, b0 * SLEN);
  }
}

// Round 6
// 266.820 us; speedup vs baseline: 8.2418x; 1.1062x over previous
//
#include <hip/hip_runtime.h>
#include <hip/hip_bf16.h>
#include <cstdint>
#include <cstddef>

#define SLEN 2048
#define NHEAD 16
#define HDIM 64

typedef short bf16x8 __attribute__((ext_vector_type(8)));
typedef float f32x4 __attribute__((ext_vector_type(4)));

__device__ __forceinline__ unsigned short f2bf(float f) {
  union { __hip_bfloat16 b; unsigned short u; } cv;
  cv.b = __float2bfloat16(f);
  return cv.u;
}

__device__ __forceinline__ unsigned pack2bf(float a, float b) {
  return (unsigned)f2bf(a) | ((unsigned)f2bf(b) << 16);
}

__device__ __forceinline__ void async16(unsigned short* lds, const unsigned short* g) {
  __builtin_amdgcn_global_load_lds(
      (const __attribute__((address_space(1))) unsigned int*)g,
      (__attribute__((address_space(3))) unsigned int*)lds, 16, 0, 0);
}

// ---------------------------------------------------------------------------
// convert x (f32) -> bf16 flat
// ---------------------------------------------------------------------------
__global__ __launch_bounds__(256) void cvt_bf16(
    const float* __restrict__ in, unsigned short* __restrict__ out, int n8)
{
  int i = blockIdx.x * 256 + threadIdx.x;
  if (i >= n8) return;
  const float4 a = *(const float4*)(in + (size_t)i*8);
  const float4 b = *(const float4*)(in + (size_t)i*8 + 4);
  ushort4 o0 = {f2bf(a.x), f2bf(a.y), f2bf(a.z), f2bf(a.w)};
  ushort4 o1 = {f2bf(b.x), f2bf(b.y), f2bf(b.z), f2bf(b.w)};
  *(ushort4*)(out + (size_t)i*8)     = o0;
  *(ushort4*)(out + (size_t)i*8 + 4) = o1;
}

// ---------------------------------------------------------------------------
// mask (f32) -> mask * log2(e)  (so softmax runs in exp2 domain)
// ---------------------------------------------------------------------------
__global__ __launch_bounds__(256) void scale_mask(
    const float* __restrict__ in, float* __restrict__ out, int n)
{
  int i = blockIdx.x * 256 + threadIdx.x;
  if (i < n) out[i] = in[i] * 1.44269504088896f;
}

// ---------------------------------------------------------------------------
// transpose W (K,N) f32 -> Wt (N,K) bf16, 32x32 LDS tiles
// ---------------------------------------------------------------------------
__global__ __launch_bounds__(256) void transpose_w(
    const float* __restrict__ W, unsigned short* __restrict__ Wt, int K, int N)
{
  __shared__ unsigned short T[32][36];
  const int kb = blockIdx.y * 32, nb = blockIdx.x * 32;
  const int r = threadIdx.x >> 3, c4 = (threadIdx.x & 7) * 4;
  float4 w = *(const float4*)(W + (size_t)(kb + r)*N + nb + c4);
  T[c4+0][r] = f2bf(w.x); T[c4+1][r] = f2bf(w.y);
  T[c4+2][r] = f2bf(w.z); T[c4+3][r] = f2bf(w.w);
  __syncthreads();
  ushort4 o = {T[r][c4], T[r][c4+1], T[r][c4+2], T[r][c4+3]};
  *(ushort4*)(Wt + (size_t)(nb + r)*K + kb + c4) = o;
}

// ---------------------------------------------------------------------------
// GEMM1 (MFMA): qkv = xb @ WattnT^T + bias. (unchanged)
// ---------------------------------------------------------------------------
__global__ __launch_bounds__(256, 2) void gemm1_mfma(
    const unsigned short* __restrict__ Xb,
    const unsigned short* __restrict__ Wt,
    const float* __restrict__ Bias,
    unsigned short* __restrict__ Qb, unsigned short* __restrict__ Kb,
    unsigned short* __restrict__ Vt, int m0)
{
  __shared__ union {
    struct { unsigned short A[128*32]; unsigned short B[128*32]; } s;
    unsigned short vt[128*136];
  } u;
  const int tid = threadIdx.x;
  const int wid = tid >> 6, lane = tid & 63;
  const int lo = lane & 15, hi = lane >> 4;
  const int wr = wid >> 1, wc = wid & 1;
  const int mtile = blockIdx.y * 128;
  const int nbase = blockIdx.x * 128;

  f32x4 acc[4][4];
  #pragma unroll
  for (int i = 0; i < 4; i++)
    #pragma unroll
    for (int j = 0; j < 4; j++) { f32x4 z = {0.f,0.f,0.f,0.f}; acc[i][j] = z; }

  const int ldrow = 32*wid + (lane >> 2);
  const int koff  = (lane & 3) * 8;

  const unsigned short* Abase = Xb + (size_t)(m0 + mtile)*1024;
  const unsigned short* Bbase = Wt + (size_t)nbase*1024;

  for (int k0 = 0; k0 < 1024; k0 += 32) {
    __syncthreads();
    #pragma unroll
    for (int cc = 0; cc < 2; cc++) {
      int r = ldrow + cc*16;
      async16(&u.s.A[r*32 + koff], Abase + (size_t)r*1024 + k0 + koff);
      async16(&u.s.B[r*32 + koff], Bbase + (size_t)r*1024 + k0 + koff);
    }
    __syncthreads();
    bf16x8 af[4], bf[4];
    #pragma unroll
    for (int mi = 0; mi < 4; mi++)
      af[mi] = *(const bf16x8*)&u.s.A[(wr*64 + mi*16 + lo)*32 + hi*8];
    #pragma unroll
    for (int ni = 0; ni < 4; ni++)
      bf[ni] = *(const bf16x8*)&u.s.B[(wc*64 + ni*16 + lo)*32 + hi*8];
    #pragma unroll
    for (int mi = 0; mi < 4; mi++)
      #pragma unroll
      for (int ni = 0; ni < 4; ni++)
        acc[mi][ni] = __builtin_amdgcn_mfma_f32_16x16x32_bf16(
            af[mi], bf[ni], acc[mi][ni], 0, 0, 0);
  }

  float bias_[4];
  #pragma unroll
  for (int ni = 0; ni < 4; ni++) bias_[ni] = Bias[nbase + wc*64 + ni*16 + lo];

  const int bl = mtile >> 11;
  const int s0 = mtile & 2047;

  if (nbase < 2048) {
    unsigned short* dst = (nbase < 1024) ? Qb : Kb;
    const int nb2 = nbase & 1023;
    #pragma unroll
    for (int mi = 0; mi < 4; mi++)
      #pragma unroll
      for (int i = 0; i < 4; i++) {
        int s = s0 + wr*64 + mi*16 + hi*4 + i;
        #pragma unroll
        for (int ni = 0; ni < 4; ni++) {
          int n = nb2 + wc*64 + ni*16 + lo;
          int h = n >> 6, d = n & 63;
          dst[((size_t)(bl*16 + h)*SLEN + s)*HDIM + d] =
              f2bf(acc[mi][ni][i] + bias_[ni]);
        }
      }
  } else {
    __syncthreads();
    #pragma unroll
    for (int mi = 0; mi < 4; mi++)
      #pragma unroll
      for (int ni = 0; ni < 4; ni++)
        #pragma unroll
        for (int i = 0; i < 4; i++) {
          int ml = wr*64 + mi*16 + hi*4 + i;
          int nl = wc*64 + ni*16 + lo;
          u.vt[nl*136 + ml] = f2bf(acc[mi][ni][i] + bias_[ni]);
        }
    __syncthreads();
    const int rv = tid >> 1, halfc = (tid & 1)*64;
    const int ng = nbase - 2048 + rv;
    const int h = ng >> 6, d = ng & 63;
    unsigned short* drow = Vt + ((size_t)(bl*16 + h)*HDIM + d)*SLEN + s0 + halfc;
    #pragma unroll
    for (int j = 0; j < 8; j++) {
      bf16x8 v = *(const bf16x8*)&u.vt[rv*136 + halfc + j*8];
      *(bf16x8*)(drow + j*8) = v;
    }
  }
}

// ---------------------------------------------------------------------------
// MFMA flash attention v3: v2 + Ps shrunk to [4][16][64] via b128-granular
// XOR swizzle (LDS 40960 B -> 4 blocks/CU) + setprio around MFMA clusters.
// ---------------------------------------------------------------------------
__global__ __launch_bounds__(256, 4) void attn_mfma(
    const unsigned short* __restrict__ Qb, const unsigned short* __restrict__ Kb,
    const unsigned short* __restrict__ Vt, const float* __restrict__ maskL,
    unsigned short* __restrict__ O, int b0)
{
  __shared__ unsigned short Ks[2][64*64];   // [buf][row*64 + chunk^(row&7) swizzled]
  __shared__ unsigned short Vs[2][64*64];   // [buf][d-row][key chunks, swizzled]
  __shared__ unsigned short Ps[4][16][64];  // [wave][q-row][key ^ ((lo&7)<<3)]

  const int tid = threadIdx.x;
  const int wid = tid >> 6, lane = tid & 63;
  const int lo = lane & 15, hi = lane >> 4;
  const int qt = blockIdx.x & 31;
  const int bh = blockIdx.x >> 5;
  const int bglob = b0 + (bh >> 4);
  const float* mrow = maskL + (size_t)bglob * SLEN;

  const unsigned short* qg = Qb + ((size_t)bh*SLEN + qt*64)*HDIM;
  const unsigned short* kg = Kb + (size_t)bh*SLEN*HDIM;
  const unsigned short* vg = Vt + (size_t)bh*HDIM*SLEN;

  // Q fragments straight from global (read once): B-operand rows = q (lane lo)
  const unsigned short* qrow = qg + (size_t)(wid*16 + lo)*HDIM;
  const bf16x8 qa0 = *(const bf16x8*)(qrow + hi*8);
  const bf16x8 qa1 = *(const bf16x8*)(qrow + 32 + hi*8);

  // staging: linear LDS dest (lane*16B), XOR-swizzled global source chunk
  auto STAGE = [&](int bu, int kt2) {
    #pragma unroll
    for (int i = 0; i < 2; i++) {
      int slot = tid + i*256;
      int row = slot >> 3, p = slot & 7;
      int c = p ^ (row & 7);
      async16(&Ks[bu][row*64 + p*8], kg + (size_t)(kt2*64 + row)*HDIM + c*8);
      async16(&Vs[bu][row*64 + p*8], vg + (size_t)row*SLEN + kt2*64 + c*8);
    }
  };

  float m_ = -INFINITY, l_ = 0.f;   // per-lane state for q-row lo (x4 replicated)
  f32x4 oacc[4];
  #pragma unroll
  for (int i = 0; i < 4; i++) { f32x4 z = {0.f,0.f,0.f,0.f}; oacc[i] = z; }

  const float SC2 = 0.125f * 1.44269504088896f;   // scale * log2(e)
  const int x7 = lo & 7;
  const int pswz = (lo & 7) << 3;

  STAGE(0, 0);
  for (int kt = 0; kt < SLEN/64; kt++) {
    const int cur = kt & 1;
    __syncthreads();                      // drains async stage of buf[cur]
    if (kt + 1 < SLEN/64) STAGE(cur ^ 1, kt + 1);   // latency hides under compute

    // ---- S^T = K Q^T : lane holds 16 scores for q-row lo ----
    f32x4 sacc[4];
    __builtin_amdgcn_s_setprio(1);
    #pragma unroll
    for (int blk = 0; blk < 4; blk++) {
      const int row = blk*16 + lo;
      bf16x8 kb0 = *(const bf16x8*)&Ks[cur][row*64 + ((hi     ^ x7)*8)];
      bf16x8 kb1 = *(const bf16x8*)&Ks[cur][row*64 + (((hi+4) ^ x7)*8)];
      f32x4 z = {0.f,0.f,0.f,0.f};
      z = __builtin_amdgcn_mfma_f32_16x16x32_bf16(kb0, qa0, z, 0, 0, 0);
      sacc[blk] = __builtin_amdgcn_mfma_f32_16x16x32_bf16(kb1, qa1, z, 0, 0, 0);
    }
    __builtin_amdgcn_s_setprio(0);

    // ---- softmax in exp2 domain ----
    float sl[4][4];
    float rmax = -INFINITY;
    #pragma unroll
    for (int blk = 0; blk < 4; blk++) {
      float4 mk = *(const float4*)(mrow + kt*64 + blk*16 + hi*4);
      sl[blk][0] = fmaf(sacc[blk][0], SC2, mk.x);
      sl[blk][1] = fmaf(sacc[blk][1], SC2, mk.y);
      sl[blk][2] = fmaf(sacc[blk][2], SC2, mk.z);
      sl[blk][3] = fmaf(sacc[blk][3], SC2, mk.w);
      #pragma unroll
      for (int i = 0; i < 4; i++) rmax = fmaxf(rmax, sl[blk][i]);
    }
    rmax = fmaxf(rmax, __shfl_xor(rmax, 16));
    rmax = fmaxf(rmax, __shfl_xor(rmax, 32));

    if (!__all(rmax <= m_ + 8.f)) {       // defer-max: rescale only when needed
      float mnew = fmaxf(m_, rmax);
      float corr = exp2f(m_ - mnew);      // -inf first iter -> 0
      m_ = mnew;
      l_ *= corr;
      float c4[4];
      #pragma unroll
      for (int i = 0; i < 4; i++) c4[i] = __shfl(corr, hi*4 + i);
      #pragma unroll
      for (int dblk = 0; dblk < 4; dblk++)
        #pragma unroll
        for (int i = 0; i < 4; i++) oacc[dblk][i] *= c4[i];
    }

    float psum = 0.f;
    #pragma unroll
    for (int blk = 0; blk < 4; blk++) {
      #pragma unroll
      for (int t = 0; t < 2; t++) {
        float p0 = exp2f(sl[blk][2*t]   - m_);
        float p1 = exp2f(sl[blk][2*t+1] - m_);
        psum += p0 + p1;
        *(unsigned*)&Ps[wid][lo][(blk*16 + hi*4 + 2*t) ^ pswz] = pack2bf(p0, p1);
      }
    }
    psum += __shfl_xor(psum, 16);
    psum += __shfl_xor(psum, 32);
    l_ += psum;

    // ---- O += P V (Ps same-wave RAW) ----
    bf16x8 pa0 = *(const bf16x8*)&Ps[wid][lo][(hi*8)      ^ pswz];
    bf16x8 pa1 = *(const bf16x8*)&Ps[wid][lo][(32 + hi*8) ^ pswz];
    __builtin_amdgcn_s_setprio(1);
    #pragma unroll
    for (int dblk = 0; dblk < 4; dblk++) {
      const int row = dblk*16 + lo;
      bf16x8 vb0 = *(const bf16x8*)&Vs[cur][row*64 + ((hi     ^ x7)*8)];
      bf16x8 vb1 = *(const bf16x8*)&Vs[cur][row*64 + (((hi+4) ^ x7)*8)];
      oacc[dblk] = __builtin_amdgcn_mfma_f32_16x16x32_bf16(pa0, vb0, oacc[dblk], 0, 0, 0);
      oacc[dblk] = __builtin_amdgcn_mfma_f32_16x16x32_bf16(pa1, vb1, oacc[dblk], 0, 0, 0);
    }
    __builtin_amdgcn_s_setprio(0);
  }

  float invl = 1.f / l_;
  float inv4[4];
  #pragma unroll
  for (int i = 0; i < 4; i++) inv4[i] = __shfl(invl, hi*4 + i);

  const size_t obase = ((size_t)bh*SLEN + qt*64 + wid*16)*HDIM;
  #pragma unroll
  for (int i = 0; i < 4; i++) {
    int row = hi*4 + i;
    #pragma unroll
    for (int dblk = 0; dblk < 4; dblk++)
      O[obase + (size_t)row*HDIM + dblk*16 + lo] = f2bf(oacc[dblk][i]*inv4[i]);
  }
}

// ---------------------------------------------------------------------------
// GEMM2 (MFMA): out = merge_heads(Ob) @ WprojT^T + bias. (unchanged)
// ---------------------------------------------------------------------------
__global__ __launch_bounds__(256, 2) void gemm2_mfma(
    const unsigned short* __restrict__ Ob,
    const unsigned short* __restrict__ Wt,
    const float* __restrict__ Bias,
    float* __restrict__ Out, int m0)
{
  __shared__ unsigned short As[128*32];
  __shared__ unsigned short Bs[128*32];
  const int tid = threadIdx.x;
  const int wid = tid >> 6, lane = tid & 63;
  const int lo = lane & 15, hi = lane >> 4;
  const int wr = wid >> 1, wc = wid & 1;
  const int mtile = blockIdx.y * 128;
  const int nbase = blockIdx.x * 128;

  f32x4 acc[4][4];
  #pragma unroll
  for (int i = 0; i < 4; i++)
    #pragma unroll
    for (int j = 0; j < 4; j++) { f32x4 z = {0.f,0.f,0.f,0.f}; acc[i][j] = z; }

  const int ldrow = 32*wid + (lane >> 2);
  const int koff  = (lane & 3) * 8;

  const int bl = mtile >> 11;
  const int s0 = mtile & 2047;
  const unsigned short* Bbase = Wt + (size_t)nbase*1024;

  for (int k0 = 0; k0 < 1024; k0 += 32) {
    const int h = k0 >> 6;
    const int dpart = (k0 & 63) + koff;
    __syncthreads();
    #pragma unroll
    for (int cc = 0; cc < 2; cc++) {
      int r = ldrow + cc*16;
      const unsigned short* ga =
          Ob + ((size_t)(bl*16 + h)*SLEN + s0 + r)*HDIM + dpart;
      async16(&As[r*32 + koff], ga);
      async16(&Bs[r*32 + koff], Bbase + (size_t)r*1024 + k0 + koff);
    }
    __syncthreads();
    bf16x8 af[4], bf[4];
    #pragma unroll
    for (int mi = 0; mi < 4; mi++)
      af[mi] = *(const bf16x8*)&As[(wr*64 + mi*16 + lo)*32 + hi*8];
    #pragma unroll
    for (int ni = 0; ni < 4; ni++)
      bf[ni] = *(const bf16x8*)&Bs[(wc*64 + ni*16 + lo)*32 + hi*8];
    #pragma unroll
    for (int mi = 0; mi < 4; mi++)
      #pragma unroll
      for (int ni = 0; ni < 4; ni++)
        acc[mi][ni] = __builtin_amdgcn_mfma_f32_16x16x32_bf16(
            af[mi], bf[ni], acc[mi][ni], 0, 0, 0);
  }

  float bias_[4];
  #pragma unroll
  for (int ni = 0; ni < 4; ni++) bias_[ni] = Bias[nbase + wc*64 + ni*16 + lo];

  #pragma unroll
  for (int mi = 0; mi < 4; mi++)
    #pragma unroll
    for (int i = 0; i < 4; i++) {
      int m = m0 + mtile + wr*64 + mi*16 + hi*4 + i;
      float* orow = Out + (size_t)m*1024 + nbase + wc*64 + lo;
      #pragma unroll
      for (int ni = 0; ni < 4; ni++)
        orow[ni*16] = acc[mi][ni][i] + bias_[ni];
    }
}

extern "C" void kernel_launch(void* const* d_in, const int* in_sizes, int n_in,
                              void* d_out, int out_size, void* d_ws, size_t ws_size,
                              hipStream_t stream) {
  const float* x     = (const float*)d_in[0];
  const float* amask = (const float*)d_in[1];
  const float* wat   = (const float*)d_in[2];
  const float* bat   = (const float*)d_in[3];
  const float* wpr   = (const float*)d_in[4];
  const float* bpr   = (const float*)d_in[5];
  float* out = (float*)d_out;

  unsigned short* WattnT = (unsigned short*)d_ws;
  unsigned short* WprojT = WattnT + (size_t)3072*1024;
  unsigned short* xb     = WprojT + (size_t)1024*1024;
  float*          maskL  = (float*)(xb + (size_t)8192*1024);
  unsigned short* chunk0 = (unsigned short*)(maskL + 4*SLEN);

  const size_t PB = (size_t)NHEAD * SLEN * HDIM;
  const size_t base_bytes = ((size_t)3072*1024 + (size_t)1024*1024 + (size_t)8192*1024) * 2
                          + (size_t)4*SLEN*4;
  int bc = 1;
  if (ws_size >= base_bytes + 4 * 4 * PB * 2)      bc = 4;
  else if (ws_size >= base_bytes + 2 * 4 * PB * 2) bc = 2;

  cvt_bf16<<<dim3((8192*1024/8 + 255)/256), dim3(256), 0, stream>>>(
      x, xb, 8192*1024/8);
  scale_mask<<<dim3((4*SLEN + 255)/256), dim3(256), 0, stream>>>(
      amask, maskL, 4*SLEN);
  transpose_w<<<dim3(3072/32, 1024/32), dim3(256), 0, stream>>>(wat, WattnT, 1024, 3072);
  transpose_w<<<dim3(1024/32, 1024/32), dim3(256), 0, stream>>>(wpr, WprojT, 1024, 1024);

  for (int b0 = 0; b0 < 4; b0 += bc) {
    unsigned short* Qb = chunk0;
    unsigned short* Kb = Qb + (size_t)bc * PB;
    unsigned short* Vt = Kb + (size_t)bc * PB;
    unsigned short* Ob = Vt + (size_t)bc * PB;
    int Mrows = bc * SLEN;
    gemm1_mfma<<<dim3(24, Mrows/128), dim3(256), 0, stream>>>(
        xb, WattnT, bat, Qb, Kb, Vt, b0 * SLEN);
    attn_mfma<<<dim3(bc * NHEAD * (SLEN/64)), dim3(256), 0, stream>>>(
        Qb, Kb, Vt, maskL, Ob, b0);
    gemm2_mfma<<<dim3(8, Mrows/128), dim3(256), 0, stream>>>(
        Ob, WprojT, bpr, out, b0 * SLEN);
  }
}

// Round 7
// 263.627 us; speedup vs baseline: 8.3417x; 1.0121x over previous
//
#include <hip/hip_runtime.h>
#include <hip/hip_bf16.h>
#include <cstdint>
#include <cstddef>

#define SLEN 2048
#define NHEAD 16
#define HDIM 64

typedef short bf16x8 __attribute__((ext_vector_type(8)));
typedef float f32x4 __attribute__((ext_vector_type(4)));

__device__ __forceinline__ unsigned short f2bf(float f) {
  union { __hip_bfloat16 b; unsigned short u; } cv;
  cv.b = __float2bfloat16(f);
  return cv.u;
}

__device__ __forceinline__ unsigned pack2bf(float a, float b) {
  return (unsigned)f2bf(a) | ((unsigned)f2bf(b) << 16);
}

__device__ __forceinline__ void async16(unsigned short* lds, const unsigned short* g) {
  __builtin_amdgcn_global_load_lds(
      (const __attribute__((address_space(1))) unsigned int*)g,
      (__attribute__((address_space(3))) unsigned int*)lds, 16, 0, 0);
}

// ---------------------------------------------------------------------------
// convert x (f32) -> bf16 flat
// ---------------------------------------------------------------------------
__global__ __launch_bounds__(256) void cvt_bf16(
    const float* __restrict__ in, unsigned short* __restrict__ out, int n8)
{
  int i = blockIdx.x * 256 + threadIdx.x;
  if (i >= n8) return;
  const float4 a = *(const float4*)(in + (size_t)i*8);
  const float4 b = *(const float4*)(in + (size_t)i*8 + 4);
  ushort4 o0 = {f2bf(a.x), f2bf(a.y), f2bf(a.z), f2bf(a.w)};
  ushort4 o1 = {f2bf(b.x), f2bf(b.y), f2bf(b.z), f2bf(b.w)};
  *(ushort4*)(out + (size_t)i*8)     = o0;
  *(ushort4*)(out + (size_t)i*8 + 4) = o1;
}

// ---------------------------------------------------------------------------
// mask (f32) -> mask * log2(e)  (exp2-domain softmax)
// ---------------------------------------------------------------------------
__global__ __launch_bounds__(256) void scale_mask(
    const float* __restrict__ in, float* __restrict__ out, int n)
{
  int i = blockIdx.x * 256 + threadIdx.x;
  if (i < n) out[i] = in[i] * 1.44269504088896f;
}

// ---------------------------------------------------------------------------
// transpose W (K,N) f32 -> Wt (N,K) bf16, 32x32 LDS tiles
// ---------------------------------------------------------------------------
__global__ __launch_bounds__(256) void transpose_w(
    const float* __restrict__ W, unsigned short* __restrict__ Wt, int K, int N)
{
  __shared__ unsigned short T[32][36];
  const int kb = blockIdx.y * 32, nb = blockIdx.x * 32;
  const int r = threadIdx.x >> 3, c4 = (threadIdx.x & 7) * 4;
  float4 w = *(const float4*)(W + (size_t)(kb + r)*N + nb + c4);
  T[c4+0][r] = f2bf(w.x); T[c4+1][r] = f2bf(w.y);
  T[c4+2][r] = f2bf(w.z); T[c4+3][r] = f2bf(w.w);
  __syncthreads();
  ushort4 o = {T[r][c4], T[r][c4+1], T[r][c4+2], T[r][c4+3]};
  *(ushort4*)(Wt + (size_t)(nb + r)*K + kb + c4) = o;
}

// ---------------------------------------------------------------------------
// GEMM1 (MFMA): qkv = xb @ WattnT^T + bias. (unchanged)
// ---------------------------------------------------------------------------
__global__ __launch_bounds__(256, 2) void gemm1_mfma(
    const unsigned short* __restrict__ Xb,
    const unsigned short* __restrict__ Wt,
    const float* __restrict__ Bias,
    unsigned short* __restrict__ Qb, unsigned short* __restrict__ Kb,
    unsigned short* __restrict__ Vt, int m0)
{
  __shared__ union {
    struct { unsigned short A[128*32]; unsigned short B[128*32]; } s;
    unsigned short vt[128*136];
  } u;
  const int tid = threadIdx.x;
  const int wid = tid >> 6, lane = tid & 63;
  const int lo = lane & 15, hi = lane >> 4;
  const int wr = wid >> 1, wc = wid & 1;
  const int mtile = blockIdx.y * 128;
  const int nbase = blockIdx.x * 128;

  f32x4 acc[4][4];
  #pragma unroll
  for (int i = 0; i < 4; i++)
    #pragma unroll
    for (int j = 0; j < 4; j++) { f32x4 z = {0.f,0.f,0.f,0.f}; acc[i][j] = z; }

  const int ldrow = 32*wid + (lane >> 2);
  const int koff  = (lane & 3) * 8;

  const unsigned short* Abase = Xb + (size_t)(m0 + mtile)*1024;
  const unsigned short* Bbase = Wt + (size_t)nbase*1024;

  for (int k0 = 0; k0 < 1024; k0 += 32) {
    __syncthreads();
    #pragma unroll
    for (int cc = 0; cc < 2; cc++) {
      int r = ldrow + cc*16;
      async16(&u.s.A[r*32 + koff], Abase + (size_t)r*1024 + k0 + koff);
      async16(&u.s.B[r*32 + koff], Bbase + (size_t)r*1024 + k0 + koff);
    }
    __syncthreads();
    bf16x8 af[4], bf[4];
    #pragma unroll
    for (int mi = 0; mi < 4; mi++)
      af[mi] = *(const bf16x8*)&u.s.A[(wr*64 + mi*16 + lo)*32 + hi*8];
    #pragma unroll
    for (int ni = 0; ni < 4; ni++)
      bf[ni] = *(const bf16x8*)&u.s.B[(wc*64 + ni*16 + lo)*32 + hi*8];
    #pragma unroll
    for (int mi = 0; mi < 4; mi++)
      #pragma unroll
      for (int ni = 0; ni < 4; ni++)
        acc[mi][ni] = __builtin_amdgcn_mfma_f32_16x16x32_bf16(
            af[mi], bf[ni], acc[mi][ni], 0, 0, 0);
  }

  float bias_[4];
  #pragma unroll
  for (int ni = 0; ni < 4; ni++) bias_[ni] = Bias[nbase + wc*64 + ni*16 + lo];

  const int bl = mtile >> 11;
  const int s0 = mtile & 2047;

  if (nbase < 2048) {
    unsigned short* dst = (nbase < 1024) ? Qb : Kb;
    const int nb2 = nbase & 1023;
    #pragma unroll
    for (int mi = 0; mi < 4; mi++)
      #pragma unroll
      for (int i = 0; i < 4; i++) {
        int s = s0 + wr*64 + mi*16 + hi*4 + i;
        #pragma unroll
        for (int ni = 0; ni < 4; ni++) {
          int n = nb2 + wc*64 + ni*16 + lo;
          int h = n >> 6, d = n & 63;
          dst[((size_t)(bl*16 + h)*SLEN + s)*HDIM + d] =
              f2bf(acc[mi][ni][i] + bias_[ni]);
        }
      }
  } else {
    __syncthreads();
    #pragma unroll
    for (int mi = 0; mi < 4; mi++)
      #pragma unroll
      for (int ni = 0; ni < 4; ni++)
        #pragma unroll
        for (int i = 0; i < 4; i++) {
          int ml = wr*64 + mi*16 + hi*4 + i;
          int nl = wc*64 + ni*16 + lo;
          u.vt[nl*136 + ml] = f2bf(acc[mi][ni][i] + bias_[ni]);
        }
    __syncthreads();
    const int rv = tid >> 1, halfc = (tid & 1)*64;
    const int ng = nbase - 2048 + rv;
    const int h = ng >> 6, d = ng & 63;
    unsigned short* drow = Vt + ((size_t)(bl*16 + h)*HDIM + d)*SLEN + s0 + halfc;
    #pragma unroll
    for (int j = 0; j < 8; j++) {
      bf16x8 v = *(const bf16x8*)&u.vt[rv*136 + halfc + j*8];
      *(bf16x8*)(drow + j*8) = v;
    }
  }
}

// ---------------------------------------------------------------------------
// MFMA flash attention v4: QBLK=128 (2 q-groups/wave, K/V staged once),
// l accumulated via ones-MFMA directly in O layout, max3 rmax tree,
// swapped QK^T + exp2 softmax + defer-max + dbuf global_load_lds staging.
// ---------------------------------------------------------------------------
__global__ __launch_bounds__(256, 4) void attn_mfma(
    const unsigned short* __restrict__ Qb, const unsigned short* __restrict__ Kb,
    const unsigned short* __restrict__ Vt, const float* __restrict__ maskL,
    unsigned short* __restrict__ O, int b0)
{
  __shared__ unsigned short Ks[2][64*64];
  __shared__ unsigned short Vs[2][64*64];
  __shared__ unsigned short Ps[4][16][64];

  const int tid = threadIdx.x;
  const int wid = tid >> 6, lane = tid & 63;
  const int lo = lane & 15, hi = lane >> 4;
  const int qt = blockIdx.x & 15;          // 128-row q tiles
  const int bh = blockIdx.x >> 4;
  const int bglob = b0 + (bh >> 4);
  const float* mrow = maskL + (size_t)bglob * SLEN;

  const unsigned short* qg = Qb + ((size_t)bh*SLEN + qt*128)*HDIM;
  const unsigned short* kg = Kb + (size_t)bh*SLEN*HDIM;
  const unsigned short* vg = Vt + (size_t)bh*HDIM*SLEN;

  // Q fragments for both groups (read once from global)
  bf16x8 qa[2][2];
  #pragma unroll
  for (int g = 0; g < 2; g++) {
    const unsigned short* qrow = qg + (size_t)(g*64 + wid*16 + lo)*HDIM;
    qa[g][0] = *(const bf16x8*)(qrow + hi*8);
    qa[g][1] = *(const bf16x8*)(qrow + 32 + hi*8);
  }

  auto STAGE = [&](int bu, int kt2) {
    #pragma unroll
    for (int i = 0; i < 2; i++) {
      int slot = tid + i*256;
      int row = slot >> 3, p = slot & 7;
      int c = p ^ (row & 7);
      async16(&Ks[bu][row*64 + p*8], kg + (size_t)(kt2*64 + row)*HDIM + c*8);
      async16(&Vs[bu][row*64 + p*8], vg + (size_t)row*SLEN + kt2*64 + c*8);
    }
  };

  float m_[2] = {-INFINITY, -INFINITY};
  f32x4 lacc[2];
  f32x4 oacc[2][4];
  #pragma unroll
  for (int g = 0; g < 2; g++) {
    f32x4 z = {0.f,0.f,0.f,0.f};
    lacc[g] = z;
    #pragma unroll
    for (int i = 0; i < 4; i++) oacc[g][i] = z;
  }

  const bf16x8 ones = {0x3F80,0x3F80,0x3F80,0x3F80,0x3F80,0x3F80,0x3F80,0x3F80};
  const float SC2 = 0.125f * 1.44269504088896f;
  const int x7 = lo & 7;
  const int pswz = (lo & 7) << 3;

  STAGE(0, 0);
  for (int kt = 0; kt < SLEN/64; kt++) {
    const int cur = kt & 1;
    __syncthreads();
    if (kt + 1 < SLEN/64) STAGE(cur ^ 1, kt + 1);

    #pragma unroll
    for (int g = 0; g < 2; g++) {
      // ---- S^T = K Q^T ----
      f32x4 sacc[4];
      __builtin_amdgcn_s_setprio(1);
      #pragma unroll
      for (int blk = 0; blk < 4; blk++) {
        const int row = blk*16 + lo;
        bf16x8 kb0 = *(const bf16x8*)&Ks[cur][row*64 + ((hi     ^ x7)*8)];
        bf16x8 kb1 = *(const bf16x8*)&Ks[cur][row*64 + (((hi+4) ^ x7)*8)];
        f32x4 z = {0.f,0.f,0.f,0.f};
        z = __builtin_amdgcn_mfma_f32_16x16x32_bf16(kb0, qa[g][0], z, 0, 0, 0);
        sacc[blk] = __builtin_amdgcn_mfma_f32_16x16x32_bf16(kb1, qa[g][1], z, 0, 0, 0);
      }
      __builtin_amdgcn_s_setprio(0);

      // ---- scale + mask (in place), rmax via max3 tree ----
      #pragma unroll
      for (int blk = 0; blk < 4; blk++) {
        float4 mk = *(const float4*)(mrow + kt*64 + blk*16 + hi*4);
        sacc[blk][0] = fmaf(sacc[blk][0], SC2, mk.x);
        sacc[blk][1] = fmaf(sacc[blk][1], SC2, mk.y);
        sacc[blk][2] = fmaf(sacc[blk][2], SC2, mk.z);
        sacc[blk][3] = fmaf(sacc[blk][3], SC2, mk.w);
      }
      float t0 = fmaxf(fmaxf(sacc[0][0], sacc[0][1]), sacc[0][2]);
      float t1 = fmaxf(fmaxf(sacc[0][3], sacc[1][0]), sacc[1][1]);
      float t2 = fmaxf(fmaxf(sacc[1][2], sacc[1][3]), sacc[2][0]);
      float t3 = fmaxf(fmaxf(sacc[2][1], sacc[2][2]), sacc[2][3]);
      float t4 = fmaxf(fmaxf(sacc[3][0], sacc[3][1]), sacc[3][2]);
      float rmax = fmaxf(fmaxf(fmaxf(t0, t1), t2),
                         fmaxf(fmaxf(t3, t4), sacc[3][3]));
      rmax = fmaxf(rmax, __shfl_xor(rmax, 16));
      rmax = fmaxf(rmax, __shfl_xor(rmax, 32));

      if (!__all(rmax <= m_[g] + 8.f)) {
        float mnew = fmaxf(m_[g], rmax);
        float corr = exp2f(m_[g] - mnew);   // -inf first iter -> 0
        m_[g] = mnew;
        float c4[4];
        #pragma unroll
        for (int i = 0; i < 4; i++) c4[i] = __shfl(corr, hi*4 + i);
        #pragma unroll
        for (int i = 0; i < 4; i++) lacc[g][i] *= c4[i];
        #pragma unroll
        for (int dblk = 0; dblk < 4; dblk++)
          #pragma unroll
          for (int i = 0; i < 4; i++) oacc[g][dblk][i] *= c4[i];
      }

      // ---- exp2 + pack to Ps ----
      #pragma unroll
      for (int blk = 0; blk < 4; blk++) {
        #pragma unroll
        for (int t = 0; t < 2; t++) {
          float p0 = exp2f(sacc[blk][2*t]   - m_[g]);
          float p1 = exp2f(sacc[blk][2*t+1] - m_[g]);
          *(unsigned*)&Ps[wid][lo][(blk*16 + hi*4 + 2*t) ^ pswz] = pack2bf(p0, p1);
        }
      }

      bf16x8 pa0 = *(const bf16x8*)&Ps[wid][lo][(hi*8)      ^ pswz];
      bf16x8 pa1 = *(const bf16x8*)&Ps[wid][lo][(32 + hi*8) ^ pswz];

      // ---- l += P·1 (row-sums, lands in O layout) ----
      lacc[g] = __builtin_amdgcn_mfma_f32_16x16x32_bf16(pa0, ones, lacc[g], 0, 0, 0);
      lacc[g] = __builtin_amdgcn_mfma_f32_16x16x32_bf16(pa1, ones, lacc[g], 0, 0, 0);

      // ---- O += P V ----
      __builtin_amdgcn_s_setprio(1);
      #pragma unroll
      for (int dblk = 0; dblk < 4; dblk++) {
        const int row = dblk*16 + lo;
        bf16x8 vb0 = *(const bf16x8*)&Vs[cur][row*64 + ((hi     ^ x7)*8)];
        bf16x8 vb1 = *(const bf16x8*)&Vs[cur][row*64 + (((hi+4) ^ x7)*8)];
        oacc[g][dblk] = __builtin_amdgcn_mfma_f32_16x16x32_bf16(pa0, vb0, oacc[g][dblk], 0, 0, 0);
        oacc[g][dblk] = __builtin_amdgcn_mfma_f32_16x16x32_bf16(pa1, vb1, oacc[g][dblk], 0, 0, 0);
      }
      __builtin_amdgcn_s_setprio(0);
    }
  }

  #pragma unroll
  for (int g = 0; g < 2; g++) {
    const size_t obase = ((size_t)bh*SLEN + qt*128 + g*64 + wid*16)*HDIM;
    #pragma unroll
    for (int i = 0; i < 4; i++) {
      float inv = 1.f / lacc[g][i];
      int row = hi*4 + i;
      #pragma unroll
      for (int dblk = 0; dblk < 4; dblk++)
        O[obase + (size_t)row*HDIM + dblk*16 + lo] = f2bf(oacc[g][dblk][i]*inv);
    }
  }
}

// ---------------------------------------------------------------------------
// GEMM2 (MFMA): out = merge_heads(Ob) @ WprojT^T + bias. (unchanged)
// ---------------------------------------------------------------------------
__global__ __launch_bounds__(256, 2) void gemm2_mfma(
    const unsigned short* __restrict__ Ob,
    const unsigned short* __restrict__ Wt,
    const float* __restrict__ Bias,
    float* __restrict__ Out, int m0)
{
  __shared__ unsigned short As[128*32];
  __shared__ unsigned short Bs[128*32];
  const int tid = threadIdx.x;
  const int wid = tid >> 6, lane = tid & 63;
  const int lo = lane & 15, hi = lane >> 4;
  const int wr = wid >> 1, wc = wid & 1;
  const int mtile = blockIdx.y * 128;
  const int nbase = blockIdx.x * 128;

  f32x4 acc[4][4];
  #pragma unroll
  for (int i = 0; i < 4; i++)
    #pragma unroll
    for (int j = 0; j < 4; j++) { f32x4 z = {0.f,0.f,0.f,0.f}; acc[i][j] = z; }

  const int ldrow = 32*wid + (lane >> 2);
  const int koff  = (lane & 3) * 8;

  const int bl = mtile >> 11;
  const int s0 = mtile & 2047;
  const unsigned short* Bbase = Wt + (size_t)nbase*1024;

  for (int k0 = 0; k0 < 1024; k0 += 32) {
    const int h = k0 >> 6;
    const int dpart = (k0 & 63) + koff;
    __syncthreads();
    #pragma unroll
    for (int cc = 0; cc < 2; cc++) {
      int r = ldrow + cc*16;
      const unsigned short* ga =
          Ob + ((size_t)(bl*16 + h)*SLEN + s0 + r)*HDIM + dpart;
      async16(&As[r*32 + koff], ga);
      async16(&Bs[r*32 + koff], Bbase + (size_t)r*1024 + k0 + koff);
    }
    __syncthreads();
    bf16x8 af[4], bf[4];
    #pragma unroll
    for (int mi = 0; mi < 4; mi++)
      af[mi] = *(const bf16x8*)&As[(wr*64 + mi*16 + lo)*32 + hi*8];
    #pragma unroll
    for (int ni = 0; ni < 4; ni++)
      bf[ni] = *(const bf16x8*)&Bs[(wc*64 + ni*16 + lo)*32 + hi*8];
    #pragma unroll
    for (int mi = 0; mi < 4; mi++)
      #pragma unroll
      for (int ni = 0; ni < 4; ni++)
        acc[mi][ni] = __builtin_amdgcn_mfma_f32_16x16x32_bf16(
            af[mi], bf[ni], acc[mi][ni], 0, 0, 0);
  }

  float bias_[4];
  #pragma unroll
  for (int ni = 0; ni < 4; ni++) bias_[ni] = Bias[nbase + wc*64 + ni*16 + lo];

  #pragma unroll
  for (int mi = 0; mi < 4; mi++)
    #pragma unroll
    for (int i = 0; i < 4; i++) {
      int m = m0 + mtile + wr*64 + mi*16 + hi*4 + i;
      float* orow = Out + (size_t)m*1024 + nbase + wc*64 + lo;
      #pragma unroll
      for (int ni = 0; ni < 4; ni++)
        orow[ni*16] = acc[mi][ni][i] + bias_[ni];
    }
}

extern "C" void kernel_launch(void* const* d_in, const int* in_sizes, int n_in,
                              void* d_out, int out_size, void* d_ws, size_t ws_size,
                              hipStream_t stream) {
  const float* x     = (const float*)d_in[0];
  const float* amask = (const float*)d_in[1];
  const float* wat   = (const float*)d_in[2];
  const float* bat   = (const float*)d_in[3];
  const float* wpr   = (const float*)d_in[4];
  const float* bpr   = (const float*)d_in[5];
  float* out = (float*)d_out;

  unsigned short* WattnT = (unsigned short*)d_ws;
  unsigned short* WprojT = WattnT + (size_t)3072*1024;
  unsigned short* xb     = WprojT + (size_t)1024*1024;
  float*          maskL  = (float*)(xb + (size_t)8192*1024);
  unsigned short* chunk0 = (unsigned short*)(maskL + 4*SLEN);

  const size_t PB = (size_t)NHEAD * SLEN * HDIM;
  const size_t base_bytes = ((size_t)3072*1024 + (size_t)1024*1024 + (size_t)8192*1024) * 2
                          + (size_t)4*SLEN*4;
  int bc = 1;
  if (ws_size >= base_bytes + 4 * 4 * PB * 2)      bc = 4;
  else if (ws_size >= base_bytes + 2 * 4 * PB * 2) bc = 2;

  cvt_bf16<<<dim3((8192*1024/8 + 255)/256), dim3(256), 0, stream>>>(
      x, xb, 8192*1024/8);
  scale_mask<<<dim3((4*SLEN + 255)/256), dim3(256), 0, stream>>>(
      amask, maskL, 4*SLEN);
  transpose_w<<<dim3(3072/32, 1024/32), dim3(256), 0, stream>>>(wat, WattnT, 1024, 3072);
  transpose_w<<<dim3(1024/32, 1024/32), dim3(256), 0, stream>>>(wpr, WprojT, 1024, 1024);

  for (int b0 = 0; b0 < 4; b0 += bc) {
    unsigned short* Qb = chunk0;
    unsigned short* Kb = Qb + (size_t)bc * PB;
    unsigned short* Vt = Kb + (size_t)bc * PB;
    unsigned short* Ob = Vt + (size_t)bc * PB;
    int Mrows = bc * SLEN;
    gemm1_mfma<<<dim3(24, Mrows/128), dim3(256), 0, stream>>>(
        xb, WattnT, bat, Qb, Kb, Vt, b0 * SLEN);
    attn_mfma<<<dim3(bc * NHEAD * (SLEN/128)), dim3(256), 0, stream>>>(
        Qb, Kb, Vt, maskL, Ob, b0);
    gemm2_mfma<<<dim3(8, Mrows/128), dim3(256), 0, stream>>>(
        Ob, WprojT, bpr, out, b0 * SLEN);
  }
}